// Round 16
// baseline (436.474 us; speedup 1.0000x reference)
//
#include <hip/hip_runtime.h>

typedef unsigned short u16;
typedef __attribute__((ext_vector_type(8))) __bf16 bf16x8;
typedef __attribute__((ext_vector_type(4))) float f32x4;

__device__ __forceinline__ float bf2f(u16 u) {
  union { unsigned int i; float f; } v; v.i = ((unsigned int)u) << 16; return v.f;
}
__device__ __forceinline__ u16 f2bf(float f) {
  union { float f; unsigned int i; } v; v.f = f;
  unsigned int u = v.i;
  return (u16)((u + 0x7fffu + ((u >> 16) & 1u)) >> 16);  // RNE
}
__device__ __forceinline__ void async16(void* lds, const void* g) {
  __builtin_amdgcn_global_load_lds(
      (const __attribute__((address_space(1))) unsigned int*)g,
      (__attribute__((address_space(3))) unsigned int*)lds, 16, 0, 0);
}

// ---------------- conversions ----------------
// 8 elems/thread; float4 loads, 16B stores. Tail c0>=496 scalar.
__global__ void k_convert_x(const float* __restrict__ x, u16* __restrict__ xb) {
  int idx = blockIdx.x * 256 + threadIdx.x;       // 65536*64 threads
  int m = idx >> 6, c0 = (idx & 63) * 8;
  u16 o[8];
  if (c0 < 496) {
    float4 v0 = *(const float4*)(x + (size_t)m * 500 + c0);
    float4 v1 = *(const float4*)(x + (size_t)m * 500 + c0 + 4);
    o[0] = f2bf(v0.x); o[1] = f2bf(v0.y); o[2] = f2bf(v0.z); o[3] = f2bf(v0.w);
    o[4] = f2bf(v1.x); o[5] = f2bf(v1.y); o[6] = f2bf(v1.z); o[7] = f2bf(v1.w);
  } else {
#pragma unroll
    for (int j = 0; j < 8; ++j) {
      int c = c0 + j;
      o[j] = f2bf((c < 500) ? x[(size_t)m * 500 + c] : 0.f);
    }
  }
  *(uint4*)(xb + (size_t)m * 512 + c0) = *(const uint4*)o;
}

// W^T, padded; for q,k the OUTPUT columns are permuted so RoPE pairs are
// adjacent: new col 2p <- old col p, new col 2p+1 <- old col p+250 (p<250).
__global__ void k_convert_w(const float* __restrict__ Wq, const float* __restrict__ Wk,
                            const float* __restrict__ Wv, u16* __restrict__ Wt) {
  int idx = blockIdx.x * 256 + threadIdx.x;       // 3*512*512
  int g = idx >> 18;
  int r = idx & 262143;
  int n = r >> 9, k = r & 511;
  const float* W = (g == 0) ? Wq : (g == 1) ? Wk : Wv;
  int orig = (g == 2) ? n : ((n & 1) ? (n >> 1) + 250 : (n >> 1));
  float v = (n < 500 && k < 500) ? W[(size_t)k * 500 + orig] : 0.f;
  Wt[idx] = f2bf(v);
}

// pair tables: cospair[t][p] = cos(t * freq_p), freq_p = 1e-4^(2*(p/2)/500)
__global__ void k_tables(float* __restrict__ cospair, float* __restrict__ sinpair) {
  int t = blockIdx.x, p = threadIdx.x;
  float c = 0.f, s = 0.f;
  if (p < 250) {
    float ex = (float)(2 * (p >> 1)) / 500.0f;
    float fr = powf(1e-4f, ex);
    float ang = (float)t * fr;
    c = cosf(ang); s = sinf(ang);
  }
  cospair[t * 256 + p] = c;
  sinpair[t * 256 + p] = s;
}

// ---------------- QKV projection GEMM + fused RoPE (8-wave, 64x64) --------
// DIAGNOSIS (R6..R15, MfmaUtil pinned at 22%): the kernel is LDS-read-BW
// bound. Per step each wave read 8KB of A frags feeding only 16 MFMA
// (N_r=2): 128KB LDS reads + 32KB writes per CU-step ~ 1900cyc at 85B/cyc
// vs 320cyc of MFMA. FIX: wave tile 64M x 64N (N_r=4) — same 8KB A-read
// now feeds 32 MFMA; FLOP per LDS-byte doubles (32 -> 64).
// Block: 8 waves (2M x 4N) on 128M x 256N; 2 M-tiles (256 rows). A via
// 4-slot LDS ring (64 KB), distance-3, counted vmcnt(4)/(2)/(0) (R14's
// proven skeleton). B remat from L2 per kk2 (4 frags = 16 VGPR live);
// compiler-inserted waits drain B before MFMA use, so the explicit vmcnt
// counts only A stages.
// VGPR BUDGET: acc 64 + a 16 + bfr 16 + addressing ~ 120; MUST stay <=128
// for 2-blocks/CU (16 waves) residency. LAUNCH BOUNDS: cap ~= 256/arg2;
// (512,2) -> 128. (512,4)->64 spills (R10); (256,3)->84 spills (R7).
__global__ __launch_bounds__(512, 2) void k_gemm_qkv(
    const u16* __restrict__ xb, const u16* __restrict__ Wt,
    const float* __restrict__ cospair, const float* __restrict__ sinpair,
    u16* __restrict__ qb, u16* __restrict__ kb, u16* __restrict__ vT) {
  __shared__ u16 As[4][128][64];   // 64 KB
  const int tid = threadIdx.x;
  const int lane = tid & 63;
  const int w = tid >> 6;              // 0..7
  const int wm = w >> 2, wn = w & 3;   // 2M x 4N wave grid on 128M x 256N
  const int lrow = lane & 15, lhi = lane >> 4;
  const int sx = lrow & 7;

  // XCD-chunked bijective swizzle: 1536 blocks, 192/XCD;
  // the 6 (g,bni) variants of one m-group adjacent (share A-panel in L2).
  int bid = blockIdx.x;
  int wk = (bid & 7) * 192 + (bid >> 3);
  int mg = wk / 6;                     // 0..255
  int j6 = wk - mg * 6;
  int g = j6 >> 1, bni = j6 & 1;
  const int bn = bni << 8;             // 0 or 256
  const int m0 = mg << 8;              // 256 rows per block

  const u16* Ab = xb + (size_t)m0 * 512;
  // wave's B base: rows g*512 + bn + wn*64 + lrow
  const u16* Bl = Wt + ((size_t)(g * 512 + bn + wn * 64) + lrow) * 512 + lhi * 8;

  // stage step S (S = mt*8 + t): A rows m0+mt*128.., cols t*64..; slot S&3
  // 512 threads -> 2 loads/thread/step
#define STAGE(S) { int mt_ = (S) >> 3, t_ = (S) & 7, buf_ = (S) & 3;          \
    _Pragma("unroll")                                                         \
    for (int ld = 0; ld < 2; ++ld) {                                          \
      int gi = ld * 512 + tid;                                                \
      int r_ = gi >> 3, c_ = gi & 7;                                          \
      async16((char*)As + buf_ * 16384 + (size_t)gi * 16,                     \
              Ab + ((size_t)(mt_ * 128 + r_)) * 512 + t_ * 64 +               \
                  ((c_ ^ (r_ & 7)) * 8));                                     \
    } }

  // compute step S: per kk2, load a[4] (LDS) + bfr[4] (L2), 16 MFMA
#define COMPUTE(S) {                                                          \
    const u16* Asl = (const u16*)As + ((S) & 3) * 8192;                       \
    const int t_ = (S) & 7;                                                   \
    _Pragma("unroll")                                                         \
    for (int kk2 = 0; kk2 < 2; ++kk2) {                                       \
      bf16x8 a[4], bfr[4];                                                    \
      _Pragma("unroll")                                                       \
      for (int mi = 0; mi < 4; ++mi)                                          \
        a[mi] = *(const bf16x8*)(Asl + (wm * 64 + mi * 16 + lrow) * 64 +      \
                                 (((kk2 * 4 + lhi) ^ sx) * 8));               \
      _Pragma("unroll")                                                       \
      for (int ni = 0; ni < 4; ++ni)                                          \
        bfr[ni] = *(const bf16x8*)(Bl + (size_t)ni * 16 * 512 + t_ * 64 +     \
                                   kk2 * 32);                                 \
      __builtin_amdgcn_s_setprio(1);                                          \
      _Pragma("unroll")                                                       \
      for (int mi = 0; mi < 4; ++mi)                                          \
        _Pragma("unroll")                                                     \
        for (int ni = 0; ni < 4; ++ni)                                        \
          acc[mi][ni] = __builtin_amdgcn_mfma_f32_16x16x32_bf16(              \
              a[mi], bfr[ni], acc[mi][ni], 0, 0, 0);                          \
      __builtin_amdgcn_s_setprio(0);                                          \
    } }

#define EPILOGUE(MT) {                                                        \
    int mb = m0 + (MT) * 128;                                                 \
    if (g < 2) {                                                              \
      u16* dst = (g == 0) ? qb : kb;                                          \
      _Pragma("unroll")                                                       \
      for (int mi = 0; mi < 4; ++mi)                                          \
        _Pragma("unroll")                                                     \
        for (int ni = 0; ni < 4; ++ni) {                                      \
          int n = bn + wn * 64 + ni * 16 + lrow;                              \
          int p = n >> 1;                                                     \
          _Pragma("unroll")                                                   \
          for (int jj = 0; jj < 4; ++jj) {                                    \
            int m = mb + wm * 64 + mi * 16 + lhi * 4 + jj;                    \
            float v = acc[mi][ni][jj];                                        \
            float o = __shfl_xor(v, 1, 64);                                   \
            int ti = (m & 255) * 256 + p;                                     \
            float c = cospair[ti], s = sinpair[ti];                           \
            float r = (n & 1) ? (o * s + v * c) : (v * c - o * s);            \
            dst[(size_t)m * 512 + n] = f2bf(r);                               \
          }                                                                   \
        }                                                                     \
    } else {                                                                  \
      _Pragma("unroll")                                                       \
      for (int mi = 0; mi < 4; ++mi)                                          \
        _Pragma("unroll")                                                     \
        for (int ni = 0; ni < 4; ++ni) {                                      \
          int n = bn + wn * 64 + ni * 16 + lrow;                              \
          _Pragma("unroll")                                                   \
          for (int jj = 0; jj < 4; ++jj) {                                    \
            int m = mb + wm * 64 + mi * 16 + lhi * 4 + jj;                    \
            vT[(size_t)(m >> 8) * 131072 + (size_t)n * 256 + (m & 255)] =     \
                f2bf(acc[mi][ni][jj]);                                        \
          }                                                                   \
        }                                                                     \
    } }

  STAGE(0); STAGE(1); STAGE(2);
  asm volatile("s_waitcnt vmcnt(4)" ::: "memory");   // tile 0 resident
  __builtin_amdgcn_s_barrier();
  asm volatile("" ::: "memory");

#pragma unroll
  for (int mt = 0; mt < 2; ++mt) {
    f32x4 acc[4][4] = {};
#pragma unroll
    for (int t = 0; t < 8; ++t) {
      const int S = mt * 8 + t;
      if (S + 3 < 16) STAGE(S + 3);
      COMPUTE(S);
      if (S < 13)       asm volatile("s_waitcnt vmcnt(4)" ::: "memory");
      else if (S == 13) asm volatile("s_waitcnt vmcnt(2)" ::: "memory");
      else if (S == 14) asm volatile("s_waitcnt vmcnt(0)" ::: "memory");
      if (S < 15) {
        __builtin_amdgcn_s_barrier();
        asm volatile("" ::: "memory");
      }
    }
    EPILOGUE(mt);
  }
#undef STAGE
#undef COMPUTE
#undef EPILOGUE
}

// ---------------- fused causal attention, ring-pipelined ----------------
// block = (q-tile of 64 rows, batch), 4 waves x 16 rows.
// K tiles [16][512] (16KB) and V tiles [256h][32s] (16KB) stream through a
// 3-slot ring (48KB), distance-2 prefetch, counted vmcnt(4) — no drains in
// the main loops. P [64][256] bf16 at +48KB. Total 80KB -> 2 blocks/CU.
__global__ __launch_bounds__(256) void k_attn(
    const u16* __restrict__ qb, const u16* __restrict__ kb,
    const u16* __restrict__ vT, float* __restrict__ out) {
  __shared__ u16 smem[40960];          // 80 KB
  u16* Ring = smem;                    // 3 x 8192 u16 (16KB slots)
  u16* Ps = smem + 24576;              // [64][256]

  const int tid = threadIdx.x;
  const int lane = tid & 63;
  const int w = tid >> 6;
  int bid = blockIdx.x;                // 1024
  int wkk = (bid & 7) * 128 + (bid >> 3);
  const int b = wkk >> 2;
  const int qt = wkk & 3;
  const int t0 = qt * 64;
  const int lrow = lane & 15, lhi = lane >> 4;
  const int sx = lrow & 7;
  const int vxor = (lrow >> 1) & 3;
  const int NT = 4 * (qt + 1);         // K tiles (16 rows each), 4..16
  const int NTB = 2 * (qt + 1);        // V s-chunks (32 each), 2..8
  const int NV = 2 * NTB;              // V tiles (s-chunk x h-half), 4..16

  // Q fragments in registers
  const u16* qrow = qb + ((size_t)(b * 256 + t0 + w * 16 + lrow)) * 512;
  bf16x8 qf[16];
#pragma unroll
  for (int kk = 0; kk < 16; ++kk)
    qf[kk] = *(const bf16x8*)(qrow + kk * 32 + lhi * 8);

  // stage K tile ST (s-rows ST*16..+15) into ring slot ST%3, pre-swizzled
#define STAGE_K(ST) {                                                         \
    _Pragma("unroll")                                                         \
    for (int ld = 0; ld < 4; ++ld) {                                          \
      int gi = ld * 256 + tid;                                                \
      int r_ = gi >> 6, c_ = gi & 63;                                         \
      async16((char*)Ring + ((ST) % 3) * 16384 + (size_t)gi * 16,             \
              kb + ((size_t)(b * 256 + (ST) * 16 + r_)) * 512 +               \
                  ((c_ ^ (r_ & 7)) * 8));                                     \
    } }

  // stage V tile f=(ST,HH): h-rows HH*256..+255, s-cols ST*32..+31
#define STAGE_V(ST, HH) {                                                     \
    _Pragma("unroll")                                                         \
    for (int ld = 0; ld < 4; ++ld) {                                          \
      int gi = ld * 256 + tid;                                                \
      int r_ = gi >> 2, c_ = gi & 3;                                          \
      async16((char*)Ring + (((ST) * 2 + (HH)) % 3) * 16384 + (size_t)gi * 16,\
              vT + (size_t)b * 131072 + ((size_t)((HH) * 256 + r_)) * 256 +   \
                  (ST) * 32 + ((c_ ^ ((r_ >> 1) & 3)) * 8));                  \
    } }

  // ---- phase A: S = Q K^T, ring-pipelined over NT 16-row K tiles ----
  f32x4 sa[16] = {};
  STAGE_K(0); STAGE_K(1);
  asm volatile("s_waitcnt vmcnt(4)" ::: "memory");
  __builtin_amdgcn_s_barrier();
  asm volatile("" ::: "memory");
#pragma unroll
  for (int st = 0; st < 16; ++st) {
    if (st < NT) {
      if (st + 2 < NT) STAGE_K(st + 2);
      const u16* Ksl = Ring + (st % 3) * 8192 + lrow * 512;
      __builtin_amdgcn_s_setprio(1);
#pragma unroll
      for (int kk = 0; kk < 16; ++kk) {
        bf16x8 bf = *(const bf16x8*)(Ksl + ((kk * 4 + lhi) ^ sx) * 8);
        sa[st] = __builtin_amdgcn_mfma_f32_16x16x32_bf16(qf[kk], bf, sa[st], 0, 0, 0);
      }
      __builtin_amdgcn_s_setprio(0);
      if (st + 2 < NT)      asm volatile("s_waitcnt vmcnt(4)" ::: "memory");
      else if (st + 1 < NT) asm volatile("s_waitcnt vmcnt(0)" ::: "memory");
      if (st + 1 < NT) {
        __builtin_amdgcn_s_barrier();
        asm volatile("" ::: "memory");
      }
    }
  }

  // ---- softmax (rows spread over 16 lrow lanes) ----
  const float scale = 0.04472135954999579f;   // 500^-0.5
  float rmax[4] = {-1e30f, -1e30f, -1e30f, -1e30f};
#pragma unroll
  for (int n = 0; n < 16; ++n) {
    int s = n * 16 + lrow;
#pragma unroll
    for (int j = 0; j < 4; ++j) {
      int t = t0 + w * 16 + lhi * 4 + j;
      float v = sa[n][j] * scale;
      if (s > t) v = -1e30f;
      sa[n][j] = v;
      rmax[j] = fmaxf(rmax[j], v);
    }
  }
#pragma unroll
  for (int j = 0; j < 4; ++j)
#pragma unroll
    for (int msk = 1; msk < 16; msk <<= 1)
      rmax[j] = fmaxf(rmax[j], __shfl_xor(rmax[j], msk, 64));
  float rsum[4] = {0.f, 0.f, 0.f, 0.f};
#pragma unroll
  for (int n = 0; n < 16; ++n)
#pragma unroll
    for (int j = 0; j < 4; ++j) {
      float p = __expf(sa[n][j] - rmax[j]);
      sa[n][j] = p;
      rsum[j] += p;
    }
#pragma unroll
  for (int j = 0; j < 4; ++j)
#pragma unroll
    for (int msk = 1; msk < 16; msk <<= 1)
      rsum[j] += __shfl_xor(rsum[j], msk, 64);
  float rinv[4];
#pragma unroll
  for (int j = 0; j < 4; ++j) rinv[j] = 1.0f / rsum[j];

  // write P (bf16) to LDS, 16B-slot swizzled
#pragma unroll
  for (int n = 0; n < 16; ++n)
#pragma unroll
    for (int j = 0; j < 4; ++j) {
      int s = n * 16 + lrow;
      int trow = w * 16 + lhi * 4 + j;
      int slot = (s >> 3) ^ (trow & 7);
      Ps[trow * 256 + slot * 8 + (s & 7)] = f2bf(sa[n][j] * rinv[j]);
    }

  // realias barrier: all K reads done + P visible before V staging
  __syncthreads();

  // ---- phase B: O = P V, ring-pipelined over NV (s-chunk, h-half) tiles --
  f32x4 o[2][16] = {};
  STAGE_V(0, 0); STAGE_V(0, 1);
  asm volatile("s_waitcnt vmcnt(4)" ::: "memory");
  __builtin_amdgcn_s_barrier();
  asm volatile("" ::: "memory");
#pragma unroll
  for (int st = 0; st < 8; ++st) {
    if (st < NTB) {
#pragma unroll
      for (int hh = 0; hh < 2; ++hh) {
        const int f = st * 2 + hh;
        if (f + 2 < NV) {
          if (hh == 0) STAGE_V(st + 1, 0) else STAGE_V(st + 1, 1);
        }
        bf16x8 pf = *(const bf16x8*)&Ps[(w * 16 + lrow) * 256 + ((st * 4 + lhi) ^ sx) * 8];
        const u16* Vsl = Ring + (f % 3) * 8192;
        __builtin_amdgcn_s_setprio(1);
#pragma unroll
        for (int ni = 0; ni < 16; ++ni) {
          bf16x8 vf = *(const bf16x8*)(Vsl + (ni * 16 + lrow) * 32 + (lhi ^ vxor) * 8);
          o[hh][ni] = __builtin_amdgcn_mfma_f32_16x16x32_bf16(pf, vf, o[hh][ni], 0, 0, 0);
        }
        __builtin_amdgcn_s_setprio(0);
        if (f + 2 < NV)      asm volatile("s_waitcnt vmcnt(4)" ::: "memory");
        else if (f + 1 < NV) asm volatile("s_waitcnt vmcnt(0)" ::: "memory");
        if (f + 1 < NV) {
          __builtin_amdgcn_s_barrier();
          asm volatile("" ::: "memory");
        }
      }
    }
  }
#undef STAGE_K
#undef STAGE_V

  // ---- epilogue ----
  const int tb = t0 + w * 16;
#pragma unroll
  for (int hh = 0; hh < 2; ++hh)
#pragma unroll
    for (int ni = 0; ni < 16; ++ni) {
      int h = hh * 256 + ni * 16 + lrow;
      if (h < 500) {
#pragma unroll
        for (int j = 0; j < 4; ++j) {
          int t = tb + lhi * 4 + j;
          out[((size_t)(b * 256 + t)) * 500 + h] = o[hh][ni][j];
        }
      }
    }
}

extern "C" void kernel_launch(void* const* d_in, const int* in_sizes, int n_in,
                              void* d_out, int out_size, void* d_ws, size_t ws_size,
                              hipStream_t stream) {
  const float* x  = (const float*)d_in[0];
  const float* Wq = (const float*)d_in[1];
  const float* Wk = (const float*)d_in[2];
  const float* Wv = (const float*)d_in[3];
  float* out = (float*)d_out;

  u16* xb = (u16*)d_ws;                 // [65536][512] bf16
  u16* qb = xb + 33554432;              // [65536][512]
  u16* kb = qb + 33554432;              // [65536][512]
  u16* vT = kb + 33554432;              // [256][512][256]
  u16* Wt = vT + 33554432;              // [1536][512]
  float* cospair = (float*)(Wt + 786432); // [256][256]
  float* sinpair = cospair + 65536;       // [256][256]

  k_convert_x<<<16384, 256, 0, stream>>>(x, xb);
  k_convert_w<<<3072, 256, 0, stream>>>(Wq, Wk, Wv, Wt);
  k_tables<<<256, 256, 0, stream>>>(cospair, sinpair);
  k_gemm_qkv<<<1536, 512, 0, stream>>>(xb, Wt, cospair, sinpair, qb, kb, vT);
  k_attn<<<1024, 256, 0, stream>>>(qb, kb, vT, out);
}

// Round 17
// 329.950 us; speedup vs baseline: 1.3228x; 1.3228x over previous
//
#include <hip/hip_runtime.h>

typedef unsigned short u16;
typedef __attribute__((ext_vector_type(8))) __bf16 bf16x8;
typedef __attribute__((ext_vector_type(4))) float f32x4;

__device__ __forceinline__ float bf2f(u16 u) {
  union { unsigned int i; float f; } v; v.i = ((unsigned int)u) << 16; return v.f;
}
__device__ __forceinline__ u16 f2bf(float f) {
  union { float f; unsigned int i; } v; v.f = f;
  unsigned int u = v.i;
  return (u16)((u + 0x7fffu + ((u >> 16) & 1u)) >> 16);  // RNE
}
__device__ __forceinline__ void async16(void* lds, const void* g) {
  __builtin_amdgcn_global_load_lds(
      (const __attribute__((address_space(1))) unsigned int*)g,
      (__attribute__((address_space(3))) unsigned int*)lds, 16, 0, 0);
}

// ---------------- conversions ----------------
// 8 elems/thread; float4 loads, 16B stores. Tail c0>=496 scalar.
__global__ void k_convert_x(const float* __restrict__ x, u16* __restrict__ xb) {
  int idx = blockIdx.x * 256 + threadIdx.x;       // 65536*64 threads
  int m = idx >> 6, c0 = (idx & 63) * 8;
  u16 o[8];
  if (c0 < 496) {
    float4 v0 = *(const float4*)(x + (size_t)m * 500 + c0);
    float4 v1 = *(const float4*)(x + (size_t)m * 500 + c0 + 4);
    o[0] = f2bf(v0.x); o[1] = f2bf(v0.y); o[2] = f2bf(v0.z); o[3] = f2bf(v0.w);
    o[4] = f2bf(v1.x); o[5] = f2bf(v1.y); o[6] = f2bf(v1.z); o[7] = f2bf(v1.w);
  } else {
#pragma unroll
    for (int j = 0; j < 8; ++j) {
      int c = c0 + j;
      o[j] = f2bf((c < 500) ? x[(size_t)m * 500 + c] : 0.f);
    }
  }
  *(uint4*)(xb + (size_t)m * 512 + c0) = *(const uint4*)o;
}

// W^T, padded; for q,k the OUTPUT columns are permuted so RoPE pairs are
// adjacent: new col 2p <- old col p, new col 2p+1 <- old col p+250 (p<250).
__global__ void k_convert_w(const float* __restrict__ Wq, const float* __restrict__ Wk,
                            const float* __restrict__ Wv, u16* __restrict__ Wt) {
  int idx = blockIdx.x * 256 + threadIdx.x;       // 3*512*512
  int g = idx >> 18;
  int r = idx & 262143;
  int n = r >> 9, k = r & 511;
  const float* W = (g == 0) ? Wq : (g == 1) ? Wk : Wv;
  int orig = (g == 2) ? n : ((n & 1) ? (n >> 1) + 250 : (n >> 1));
  float v = (n < 500 && k < 500) ? W[(size_t)k * 500 + orig] : 0.f;
  Wt[idx] = f2bf(v);
}

// pair tables: cospair[t][p] = cos(t * freq_p), freq_p = 1e-4^(2*(p/2)/500)
__global__ void k_tables(float* __restrict__ cospair, float* __restrict__ sinpair) {
  int t = blockIdx.x, p = threadIdx.x;
  float c = 0.f, s = 0.f;
  if (p < 250) {
    float ex = (float)(2 * (p >> 1)) / 500.0f;
    float fr = powf(1e-4f, ex);
    float ang = (float)t * fr;
    c = cosf(ang); s = sinf(ang);
  }
  cospair[t * 256 + p] = c;
  sinpair[t * 256 + p] = s;
}

// ---------------- QKV projection GEMM + fused RoPE (8-wave, R14 config) ---
// VERIFIED BEST (R14: 190us, MfmaUtil 22.5%, VGPR 120). Block: 512 threads
// = 8 waves (2M x 4N) on 128M x 128N per M-tile; 4 M-tiles (512 rows).
// Wave tile 64x32, B-slice remat from L2. A via 4-slot LDS ring (64 KB),
// distance-3, counted vmcnt(4)/(2)/(0).
// STRUCTURAL CEILING NOTE (R11-R16 experiments, all neutral/negative):
//   - barrier-halving (R12): neutral -> not barrier-count-bound.
//   - B double-buffer w/ fences (R13): -60% (fences defeat scheduler).
//   - B in LDS, dist-1 drain (R15): -21% (drain antipattern + LDS traffic).
//   - 64x64 wave tile (R16): -59% (B L2-latency into MFMA cluster).
//   This 2-phase structure is at ~92% of its class (m230); the next step
//   is a faithful m201 8-phase port (+~29%, m248), not parameter tweaks.
// LAUNCH BOUNDS: cap ~= 256/arg2. (512,2) -> 128 VGPR ok. (512,4)->64
// spills (R10: 2.2x); (256,3)->84 spills (R7: 3x). Do not change arg2.
__global__ __launch_bounds__(512, 2) void k_gemm_qkv(
    const u16* __restrict__ xb, const u16* __restrict__ Wt,
    const float* __restrict__ cospair, const float* __restrict__ sinpair,
    u16* __restrict__ qb, u16* __restrict__ kb, u16* __restrict__ vT) {
  __shared__ u16 As[4][128][64];   // 64 KB
  const int tid = threadIdx.x;
  const int lane = tid & 63;
  const int w = tid >> 6;              // 0..7
  const int wm = w >> 2, wn = w & 3;   // 2M x 4N wave grid on 128M x 128N
  const int lrow = lane & 15, lhi = lane >> 4;
  const int sx = lrow & 7;

  // XCD-chunked bijective swizzle: 1536 blocks, 192/XCD;
  // the 12 (g,bn) variants of one m-group adjacent (share A-panel in L2).
  int bid = blockIdx.x;
  int wk = (bid & 7) * 192 + (bid >> 3);
  int mg = wk / 12;
  int j12 = wk - mg * 12;
  int g = j12 >> 2, bni = j12 & 3;
  const int bn = bni << 7;             // 0,128,256,384
  const int m0 = mg << 9;              // 512 rows per block

  const u16* Ab = xb + (size_t)m0 * 512;

  // ---- B slice in registers (once, from L2): 32 cols per wave ----
  bf16x8 breg[8][2][2];
  {
    const u16* Bl = Wt + ((size_t)(g * 512 + bn + wn * 32) + lrow) * 512 + lhi * 8;
#pragma unroll
    for (int t = 0; t < 8; ++t)
#pragma unroll
      for (int ni = 0; ni < 2; ++ni)
#pragma unroll
        for (int kk2 = 0; kk2 < 2; ++kk2)
          breg[t][ni][kk2] =
              *(const bf16x8*)(Bl + (size_t)ni * 16 * 512 + t * 64 + kk2 * 32);
  }

  // stage step S (S = mt*8 + t): A rows m0+mt*128.., cols t*64..; slot S&3
  // 512 threads -> 2 loads/thread/step
#define STAGE(S) { int mt_ = (S) >> 3, t_ = (S) & 7, buf_ = (S) & 3;          \
    _Pragma("unroll")                                                         \
    for (int ld = 0; ld < 2; ++ld) {                                          \
      int gi = ld * 512 + tid;                                                \
      int r_ = gi >> 3, c_ = gi & 7;                                          \
      async16((char*)As + buf_ * 16384 + (size_t)gi * 16,                     \
              Ab + ((size_t)(mt_ * 128 + r_)) * 512 + t_ * 64 +               \
                  ((c_ ^ (r_ & 7)) * 8));                                     \
    } }

#define AFRAGS(S)                                                             \
    const u16* Asl = (const u16*)As + ((S) & 3) * 8192;                       \
    bf16x8 a[4][2];                                                           \
    _Pragma("unroll")                                                         \
    for (int mi = 0; mi < 4; ++mi)                                            \
      _Pragma("unroll")                                                       \
      for (int kk2 = 0; kk2 < 2; ++kk2)                                       \
        a[mi][kk2] = *(const bf16x8*)(Asl + (wm * 64 + mi * 16 + lrow) * 64 + \
                                      (((kk2 * 4 + lhi) ^ sx) * 8));

#define EPILOGUE(MT) {                                                        \
    int mb = m0 + (MT) * 128;                                                 \
    if (g < 2) {                                                              \
      u16* dst = (g == 0) ? qb : kb;                                          \
      _Pragma("unroll")                                                       \
      for (int mi = 0; mi < 4; ++mi)                                          \
        _Pragma("unroll")                                                     \
        for (int ni = 0; ni < 2; ++ni) {                                      \
          int n = bn + wn * 32 + ni * 16 + lrow;                              \
          int p = n >> 1;                                                     \
          _Pragma("unroll")                                                   \
          for (int jj = 0; jj < 4; ++jj) {                                    \
            int m = mb + wm * 64 + mi * 16 + lhi * 4 + jj;                    \
            float v = acc[mi][ni][jj];                                        \
            float o = __shfl_xor(v, 1, 64);                                   \
            int ti = (m & 255) * 256 + p;                                     \
            float c = cospair[ti], s = sinpair[ti];                           \
            float r = (n & 1) ? (o * s + v * c) : (v * c - o * s);            \
            dst[(size_t)m * 512 + n] = f2bf(r);                               \
          }                                                                   \
        }                                                                     \
    } else {                                                                  \
      _Pragma("unroll")                                                       \
      for (int mi = 0; mi < 4; ++mi)                                          \
        _Pragma("unroll")                                                     \
        for (int ni = 0; ni < 2; ++ni) {                                      \
          int n = bn + wn * 32 + ni * 16 + lrow;                              \
          _Pragma("unroll")                                                   \
          for (int jj = 0; jj < 4; ++jj) {                                    \
            int m = mb + wm * 64 + mi * 16 + lhi * 4 + jj;                    \
            vT[(size_t)(m >> 8) * 131072 + (size_t)n * 256 + (m & 255)] =     \
                f2bf(acc[mi][ni][jj]);                                        \
          }                                                                   \
        }                                                                     \
    } }

  STAGE(0); STAGE(1); STAGE(2);
  asm volatile("s_waitcnt vmcnt(4)" ::: "memory");   // tile 0 resident
  __builtin_amdgcn_s_barrier();
  asm volatile("" ::: "memory");

  for (int mt = 0; mt < 3; ++mt) {
    f32x4 acc[4][2] = {};
#pragma unroll
    for (int t = 0; t < 8; ++t) {
      STAGE(mt * 8 + t + 3);
      AFRAGS(t);
      __builtin_amdgcn_s_setprio(1);
#pragma unroll
      for (int kk2 = 0; kk2 < 2; ++kk2)
#pragma unroll
        for (int mi = 0; mi < 4; ++mi)
#pragma unroll
          for (int ni = 0; ni < 2; ++ni)
            acc[mi][ni] = __builtin_amdgcn_mfma_f32_16x16x32_bf16(
                a[mi][kk2], breg[t][ni][kk2], acc[mi][ni], 0, 0, 0);
      __builtin_amdgcn_s_setprio(0);
      asm volatile("s_waitcnt vmcnt(4)" ::: "memory");
      __builtin_amdgcn_s_barrier();
      asm volatile("" ::: "memory");
    }
    EPILOGUE(mt);
  }
  {                                                  // mt = 3 (tail)
    f32x4 acc[4][2] = {};
#pragma unroll
    for (int t = 0; t < 8; ++t) {
      if (t < 5) STAGE(27 + t);
      AFRAGS(t);
      __builtin_amdgcn_s_setprio(1);
#pragma unroll
      for (int kk2 = 0; kk2 < 2; ++kk2)
#pragma unroll
        for (int mi = 0; mi < 4; ++mi)
#pragma unroll
          for (int ni = 0; ni < 2; ++ni)
            acc[mi][ni] = __builtin_amdgcn_mfma_f32_16x16x32_bf16(
                a[mi][kk2], breg[t][ni][kk2], acc[mi][ni], 0, 0, 0);
      __builtin_amdgcn_s_setprio(0);
      if (t < 5)       asm volatile("s_waitcnt vmcnt(4)" ::: "memory");
      else if (t == 5) asm volatile("s_waitcnt vmcnt(2)" ::: "memory");
      else if (t == 6) asm volatile("s_waitcnt vmcnt(0)" ::: "memory");
      if (t < 7) {
        __builtin_amdgcn_s_barrier();
        asm volatile("" ::: "memory");
      }
    }
    EPILOGUE(3);
  }
#undef STAGE
#undef AFRAGS
#undef EPILOGUE
}

// ---------------- fused causal attention, ring-pipelined ----------------
// block = (q-tile of 64 rows, batch), 4 waves x 16 rows.
// K tiles [16][512] (16KB) and V tiles [256h][32s] (16KB) stream through a
// 3-slot ring (48KB), distance-2 prefetch, counted vmcnt(4) — no drains in
// the main loops. P [64][256] bf16 at +48KB. Total 80KB -> 2 blocks/CU.
__global__ __launch_bounds__(256) void k_attn(
    const u16* __restrict__ qb, const u16* __restrict__ kb,
    const u16* __restrict__ vT, float* __restrict__ out) {
  __shared__ u16 smem[40960];          // 80 KB
  u16* Ring = smem;                    // 3 x 8192 u16 (16KB slots)
  u16* Ps = smem + 24576;              // [64][256]

  const int tid = threadIdx.x;
  const int lane = tid & 63;
  const int w = tid >> 6;
  int bid = blockIdx.x;                // 1024
  int wkk = (bid & 7) * 128 + (bid >> 3);
  const int b = wkk >> 2;
  const int qt = wkk & 3;
  const int t0 = qt * 64;
  const int lrow = lane & 15, lhi = lane >> 4;
  const int sx = lrow & 7;
  const int vxor = (lrow >> 1) & 3;
  const int NT = 4 * (qt + 1);         // K tiles (16 rows each), 4..16
  const int NTB = 2 * (qt + 1);        // V s-chunks (32 each), 2..8
  const int NV = 2 * NTB;              // V tiles (s-chunk x h-half), 4..16

  // Q fragments in registers
  const u16* qrow = qb + ((size_t)(b * 256 + t0 + w * 16 + lrow)) * 512;
  bf16x8 qf[16];
#pragma unroll
  for (int kk = 0; kk < 16; ++kk)
    qf[kk] = *(const bf16x8*)(qrow + kk * 32 + lhi * 8);

  // stage K tile ST (s-rows ST*16..+15) into ring slot ST%3, pre-swizzled
#define STAGE_K(ST) {                                                         \
    _Pragma("unroll")                                                         \
    for (int ld = 0; ld < 4; ++ld) {                                          \
      int gi = ld * 256 + tid;                                                \
      int r_ = gi >> 6, c_ = gi & 63;                                         \
      async16((char*)Ring + ((ST) % 3) * 16384 + (size_t)gi * 16,             \
              kb + ((size_t)(b * 256 + (ST) * 16 + r_)) * 512 +               \
                  ((c_ ^ (r_ & 7)) * 8));                                     \
    } }

  // stage V tile f=(ST,HH): h-rows HH*256..+255, s-cols ST*32..+31
#define STAGE_V(ST, HH) {                                                     \
    _Pragma("unroll")                                                         \
    for (int ld = 0; ld < 4; ++ld) {                                          \
      int gi = ld * 256 + tid;                                                \
      int r_ = gi >> 2, c_ = gi & 3;                                          \
      async16((char*)Ring + (((ST) * 2 + (HH)) % 3) * 16384 + (size_t)gi * 16,\
              vT + (size_t)b * 131072 + ((size_t)((HH) * 256 + r_)) * 256 +   \
                  (ST) * 32 + ((c_ ^ ((r_ >> 1) & 3)) * 8));                  \
    } }

  // ---- phase A: S = Q K^T, ring-pipelined over NT 16-row K tiles ----
  f32x4 sa[16] = {};
  STAGE_K(0); STAGE_K(1);
  asm volatile("s_waitcnt vmcnt(4)" ::: "memory");
  __builtin_amdgcn_s_barrier();
  asm volatile("" ::: "memory");
#pragma unroll
  for (int st = 0; st < 16; ++st) {
    if (st < NT) {
      if (st + 2 < NT) STAGE_K(st + 2);
      const u16* Ksl = Ring + (st % 3) * 8192 + lrow * 512;
      __builtin_amdgcn_s_setprio(1);
#pragma unroll
      for (int kk = 0; kk < 16; ++kk) {
        bf16x8 bf = *(const bf16x8*)(Ksl + ((kk * 4 + lhi) ^ sx) * 8);
        sa[st] = __builtin_amdgcn_mfma_f32_16x16x32_bf16(qf[kk], bf, sa[st], 0, 0, 0);
      }
      __builtin_amdgcn_s_setprio(0);
      if (st + 2 < NT)      asm volatile("s_waitcnt vmcnt(4)" ::: "memory");
      else if (st + 1 < NT) asm volatile("s_waitcnt vmcnt(0)" ::: "memory");
      if (st + 1 < NT) {
        __builtin_amdgcn_s_barrier();
        asm volatile("" ::: "memory");
      }
    }
  }

  // ---- softmax (rows spread over 16 lrow lanes) ----
  const float scale = 0.04472135954999579f;   // 500^-0.5
  float rmax[4] = {-1e30f, -1e30f, -1e30f, -1e30f};
#pragma unroll
  for (int n = 0; n < 16; ++n) {
    int s = n * 16 + lrow;
#pragma unroll
    for (int j = 0; j < 4; ++j) {
      int t = t0 + w * 16 + lhi * 4 + j;
      float v = sa[n][j] * scale;
      if (s > t) v = -1e30f;
      sa[n][j] = v;
      rmax[j] = fmaxf(rmax[j], v);
    }
  }
#pragma unroll
  for (int j = 0; j < 4; ++j)
#pragma unroll
    for (int msk = 1; msk < 16; msk <<= 1)
      rmax[j] = fmaxf(rmax[j], __shfl_xor(rmax[j], msk, 64));
  float rsum[4] = {0.f, 0.f, 0.f, 0.f};
#pragma unroll
  for (int n = 0; n < 16; ++n)
#pragma unroll
    for (int j = 0; j < 4; ++j) {
      float p = __expf(sa[n][j] - rmax[j]);
      sa[n][j] = p;
      rsum[j] += p;
    }
#pragma unroll
  for (int j = 0; j < 4; ++j)
#pragma unroll
    for (int msk = 1; msk < 16; msk <<= 1)
      rsum[j] += __shfl_xor(rsum[j], msk, 64);
  float rinv[4];
#pragma unroll
  for (int j = 0; j < 4; ++j) rinv[j] = 1.0f / rsum[j];

  // write P (bf16) to LDS, 16B-slot swizzled
#pragma unroll
  for (int n = 0; n < 16; ++n)
#pragma unroll
    for (int j = 0; j < 4; ++j) {
      int s = n * 16 + lrow;
      int trow = w * 16 + lhi * 4 + j;
      int slot = (s >> 3) ^ (trow & 7);
      Ps[trow * 256 + slot * 8 + (s & 7)] = f2bf(sa[n][j] * rinv[j]);
    }

  // realias barrier: all K reads done + P visible before V staging
  __syncthreads();

  // ---- phase B: O = P V, ring-pipelined over NV (s-chunk, h-half) tiles --
  f32x4 o[2][16] = {};
  STAGE_V(0, 0); STAGE_V(0, 1);
  asm volatile("s_waitcnt vmcnt(4)" ::: "memory");
  __builtin_amdgcn_s_barrier();
  asm volatile("" ::: "memory");
#pragma unroll
  for (int st = 0; st < 8; ++st) {
    if (st < NTB) {
#pragma unroll
      for (int hh = 0; hh < 2; ++hh) {
        const int f = st * 2 + hh;
        if (f + 2 < NV) {
          if (hh == 0) STAGE_V(st + 1, 0) else STAGE_V(st + 1, 1);
        }
        bf16x8 pf = *(const bf16x8*)&Ps[(w * 16 + lrow) * 256 + ((st * 4 + lhi) ^ sx) * 8];
        const u16* Vsl = Ring + (f % 3) * 8192;
        __builtin_amdgcn_s_setprio(1);
#pragma unroll
        for (int ni = 0; ni < 16; ++ni) {
          bf16x8 vf = *(const bf16x8*)(Vsl + (ni * 16 + lrow) * 32 + (lhi ^ vxor) * 8);
          o[hh][ni] = __builtin_amdgcn_mfma_f32_16x16x32_bf16(pf, vf, o[hh][ni], 0, 0, 0);
        }
        __builtin_amdgcn_s_setprio(0);
        if (f + 2 < NV)      asm volatile("s_waitcnt vmcnt(4)" ::: "memory");
        else if (f + 1 < NV) asm volatile("s_waitcnt vmcnt(0)" ::: "memory");
        if (f + 1 < NV) {
          __builtin_amdgcn_s_barrier();
          asm volatile("" ::: "memory");
        }
      }
    }
  }
#undef STAGE_K
#undef STAGE_V

  // ---- epilogue ----
  const int tb = t0 + w * 16;
#pragma unroll
  for (int hh = 0; hh < 2; ++hh)
#pragma unroll
    for (int ni = 0; ni < 16; ++ni) {
      int h = hh * 256 + ni * 16 + lrow;
      if (h < 500) {
#pragma unroll
        for (int j = 0; j < 4; ++j) {
          int t = tb + lhi * 4 + j;
          out[((size_t)(b * 256 + t)) * 500 + h] = o[hh][ni][j];
        }
      }
    }
}

extern "C" void kernel_launch(void* const* d_in, const int* in_sizes, int n_in,
                              void* d_out, int out_size, void* d_ws, size_t ws_size,
                              hipStream_t stream) {
  const float* x  = (const float*)d_in[0];
  const float* Wq = (const float*)d_in[1];
  const float* Wk = (const float*)d_in[2];
  const float* Wv = (const float*)d_in[3];
  float* out = (float*)d_out;

  u16* xb = (u16*)d_ws;                 // [65536][512] bf16
  u16* qb = xb + 33554432;              // [65536][512]
  u16* kb = qb + 33554432;              // [65536][512]
  u16* vT = kb + 33554432;              // [256][512][256]
  u16* Wt = vT + 33554432;              // [1536][512]
  float* cospair = (float*)(Wt + 786432); // [256][256]
  float* sinpair = cospair + 65536;       // [256][256]

  k_convert_x<<<16384, 256, 0, stream>>>(x, xb);
  k_convert_w<<<3072, 256, 0, stream>>>(Wq, Wk, Wv, Wt);
  k_tables<<<256, 256, 0, stream>>>(cospair, sinpair);
  k_gemm_qkv<<<1536, 512, 0, stream>>>(xb, Wt, cospair, sinpair, qb, kb, vT);
  k_attn<<<1024, 256, 0, stream>>>(qb, kb, vT, out);
}

// Round 18
// 312.656 us; speedup vs baseline: 1.3960x; 1.0553x over previous
//
#include <hip/hip_runtime.h>

typedef unsigned short u16;
typedef __attribute__((ext_vector_type(8))) __bf16 bf16x8;
typedef __attribute__((ext_vector_type(4))) float f32x4;

__device__ __forceinline__ float bf2f(u16 u) {
  union { unsigned int i; float f; } v; v.i = ((unsigned int)u) << 16; return v.f;
}
__device__ __forceinline__ u16 f2bf(float f) {
  union { float f; unsigned int i; } v; v.f = f;
  unsigned int u = v.i;
  return (u16)((u + 0x7fffu + ((u >> 16) & 1u)) >> 16);  // RNE
}
__device__ __forceinline__ void async16(void* lds, const void* g) {
  __builtin_amdgcn_global_load_lds(
      (const __attribute__((address_space(1))) unsigned int*)g,
      (__attribute__((address_space(3))) unsigned int*)lds, 16, 0, 0);
}

// ---------------- conversions ----------------
// 8 elems/thread; float4 loads, 16B stores. Tail c0>=496 scalar.
__global__ void k_convert_x(const float* __restrict__ x, u16* __restrict__ xb) {
  int idx = blockIdx.x * 256 + threadIdx.x;       // 65536*64 threads
  int m = idx >> 6, c0 = (idx & 63) * 8;
  u16 o[8];
  if (c0 < 496) {
    float4 v0 = *(const float4*)(x + (size_t)m * 500 + c0);
    float4 v1 = *(const float4*)(x + (size_t)m * 500 + c0 + 4);
    o[0] = f2bf(v0.x); o[1] = f2bf(v0.y); o[2] = f2bf(v0.z); o[3] = f2bf(v0.w);
    o[4] = f2bf(v1.x); o[5] = f2bf(v1.y); o[6] = f2bf(v1.z); o[7] = f2bf(v1.w);
  } else {
#pragma unroll
    for (int j = 0; j < 8; ++j) {
      int c = c0 + j;
      o[j] = f2bf((c < 500) ? x[(size_t)m * 500 + c] : 0.f);
    }
  }
  *(uint4*)(xb + (size_t)m * 512 + c0) = *(const uint4*)o;
}

// W^T, padded; for q,k the OUTPUT columns are permuted so RoPE pairs are
// adjacent: new col 2p <- old col p, new col 2p+1 <- old col p+250 (p<250).
__global__ void k_convert_w(const float* __restrict__ Wq, const float* __restrict__ Wk,
                            const float* __restrict__ Wv, u16* __restrict__ Wt) {
  int idx = blockIdx.x * 256 + threadIdx.x;       // 3*512*512
  int g = idx >> 18;
  int r = idx & 262143;
  int n = r >> 9, k = r & 511;
  const float* W = (g == 0) ? Wq : (g == 1) ? Wk : Wv;
  int orig = (g == 2) ? n : ((n & 1) ? (n >> 1) + 250 : (n >> 1));
  float v = (n < 500 && k < 500) ? W[(size_t)k * 500 + orig] : 0.f;
  Wt[idx] = f2bf(v);
}

// pair tables: cospair[t][p] = cos(t * freq_p), freq_p = 1e-4^(2*(p/2)/500)
__global__ void k_tables(float* __restrict__ cospair, float* __restrict__ sinpair) {
  int t = blockIdx.x, p = threadIdx.x;
  float c = 0.f, s = 0.f;
  if (p < 250) {
    float ex = (float)(2 * (p >> 1)) / 500.0f;
    float fr = powf(1e-4f, ex);
    float ang = (float)t * fr;
    c = cosf(ang); s = sinf(ang);
  }
  cospair[t * 256 + p] = c;
  sinpair[t * 256 + p] = s;
}

// ---------------- QKV projection GEMM + fused RoPE (8-wave, R14 config) ---
// VERIFIED BEST (190-195us, MfmaUtil 22.5%, VGPR 120). Do not touch —
// R11-R16 parameter/structure experiments all neutral or negative; next
// step here is a faithful m201 8-phase port only.
// LAUNCH BOUNDS: cap ~= 256/arg2. (512,2)->128 ok; (512,4)->64 spills
// (R10); (256,3)->84 spills (R7).
__global__ __launch_bounds__(512, 2) void k_gemm_qkv(
    const u16* __restrict__ xb, const u16* __restrict__ Wt,
    const float* __restrict__ cospair, const float* __restrict__ sinpair,
    u16* __restrict__ qb, u16* __restrict__ kb, u16* __restrict__ vT) {
  __shared__ u16 As[4][128][64];   // 64 KB
  const int tid = threadIdx.x;
  const int lane = tid & 63;
  const int w = tid >> 6;              // 0..7
  const int wm = w >> 2, wn = w & 3;   // 2M x 4N wave grid on 128M x 128N
  const int lrow = lane & 15, lhi = lane >> 4;
  const int sx = lrow & 7;

  int bid = blockIdx.x;
  int wk = (bid & 7) * 192 + (bid >> 3);
  int mg = wk / 12;
  int j12 = wk - mg * 12;
  int g = j12 >> 2, bni = j12 & 3;
  const int bn = bni << 7;             // 0,128,256,384
  const int m0 = mg << 9;              // 512 rows per block

  const u16* Ab = xb + (size_t)m0 * 512;

  bf16x8 breg[8][2][2];
  {
    const u16* Bl = Wt + ((size_t)(g * 512 + bn + wn * 32) + lrow) * 512 + lhi * 8;
#pragma unroll
    for (int t = 0; t < 8; ++t)
#pragma unroll
      for (int ni = 0; ni < 2; ++ni)
#pragma unroll
        for (int kk2 = 0; kk2 < 2; ++kk2)
          breg[t][ni][kk2] =
              *(const bf16x8*)(Bl + (size_t)ni * 16 * 512 + t * 64 + kk2 * 32);
  }

#define STAGE(S) { int mt_ = (S) >> 3, t_ = (S) & 7, buf_ = (S) & 3;          \
    _Pragma("unroll")                                                         \
    for (int ld = 0; ld < 2; ++ld) {                                          \
      int gi = ld * 512 + tid;                                                \
      int r_ = gi >> 3, c_ = gi & 7;                                          \
      async16((char*)As + buf_ * 16384 + (size_t)gi * 16,                     \
              Ab + ((size_t)(mt_ * 128 + r_)) * 512 + t_ * 64 +               \
                  ((c_ ^ (r_ & 7)) * 8));                                     \
    } }

#define AFRAGS(S)                                                             \
    const u16* Asl = (const u16*)As + ((S) & 3) * 8192;                       \
    bf16x8 a[4][2];                                                           \
    _Pragma("unroll")                                                         \
    for (int mi = 0; mi < 4; ++mi)                                            \
      _Pragma("unroll")                                                       \
      for (int kk2 = 0; kk2 < 2; ++kk2)                                       \
        a[mi][kk2] = *(const bf16x8*)(Asl + (wm * 64 + mi * 16 + lrow) * 64 + \
                                      (((kk2 * 4 + lhi) ^ sx) * 8));

#define EPILOGUE(MT) {                                                        \
    int mb = m0 + (MT) * 128;                                                 \
    if (g < 2) {                                                              \
      u16* dst = (g == 0) ? qb : kb;                                          \
      _Pragma("unroll")                                                       \
      for (int mi = 0; mi < 4; ++mi)                                          \
        _Pragma("unroll")                                                     \
        for (int ni = 0; ni < 2; ++ni) {                                      \
          int n = bn + wn * 32 + ni * 16 + lrow;                              \
          int p = n >> 1;                                                     \
          _Pragma("unroll")                                                   \
          for (int jj = 0; jj < 4; ++jj) {                                    \
            int m = mb + wm * 64 + mi * 16 + lhi * 4 + jj;                    \
            float v = acc[mi][ni][jj];                                        \
            float o = __shfl_xor(v, 1, 64);                                   \
            int ti = (m & 255) * 256 + p;                                     \
            float c = cospair[ti], s = sinpair[ti];                           \
            float r = (n & 1) ? (o * s + v * c) : (v * c - o * s);            \
            dst[(size_t)m * 512 + n] = f2bf(r);                               \
          }                                                                   \
        }                                                                     \
    } else {                                                                  \
      _Pragma("unroll")                                                       \
      for (int mi = 0; mi < 4; ++mi)                                          \
        _Pragma("unroll")                                                     \
        for (int ni = 0; ni < 2; ++ni) {                                      \
          int n = bn + wn * 32 + ni * 16 + lrow;                              \
          _Pragma("unroll")                                                   \
          for (int jj = 0; jj < 4; ++jj) {                                    \
            int m = mb + wm * 64 + mi * 16 + lhi * 4 + jj;                    \
            vT[(size_t)(m >> 8) * 131072 + (size_t)n * 256 + (m & 255)] =     \
                f2bf(acc[mi][ni][jj]);                                        \
          }                                                                   \
        }                                                                     \
    } }

  STAGE(0); STAGE(1); STAGE(2);
  asm volatile("s_waitcnt vmcnt(4)" ::: "memory");   // tile 0 resident
  __builtin_amdgcn_s_barrier();
  asm volatile("" ::: "memory");

  for (int mt = 0; mt < 3; ++mt) {
    f32x4 acc[4][2] = {};
#pragma unroll
    for (int t = 0; t < 8; ++t) {
      STAGE(mt * 8 + t + 3);
      AFRAGS(t);
      __builtin_amdgcn_s_setprio(1);
#pragma unroll
      for (int kk2 = 0; kk2 < 2; ++kk2)
#pragma unroll
        for (int mi = 0; mi < 4; ++mi)
#pragma unroll
          for (int ni = 0; ni < 2; ++ni)
            acc[mi][ni] = __builtin_amdgcn_mfma_f32_16x16x32_bf16(
                a[mi][kk2], breg[t][ni][kk2], acc[mi][ni], 0, 0, 0);
      __builtin_amdgcn_s_setprio(0);
      asm volatile("s_waitcnt vmcnt(4)" ::: "memory");
      __builtin_amdgcn_s_barrier();
      asm volatile("" ::: "memory");
    }
    EPILOGUE(mt);
  }
  {                                                  // mt = 3 (tail)
    f32x4 acc[4][2] = {};
#pragma unroll
    for (int t = 0; t < 8; ++t) {
      if (t < 5) STAGE(27 + t);
      AFRAGS(t);
      __builtin_amdgcn_s_setprio(1);
#pragma unroll
      for (int kk2 = 0; kk2 < 2; ++kk2)
#pragma unroll
        for (int mi = 0; mi < 4; ++mi)
#pragma unroll
          for (int ni = 0; ni < 2; ++ni)
            acc[mi][ni] = __builtin_amdgcn_mfma_f32_16x16x32_bf16(
                a[mi][kk2], breg[t][ni][kk2], acc[mi][ni], 0, 0, 0);
      __builtin_amdgcn_s_setprio(0);
      if (t < 5)       asm volatile("s_waitcnt vmcnt(4)" ::: "memory");
      else if (t == 5) asm volatile("s_waitcnt vmcnt(2)" ::: "memory");
      else if (t == 6) asm volatile("s_waitcnt vmcnt(0)" ::: "memory");
      if (t < 7) {
        __builtin_amdgcn_s_barrier();
        asm volatile("" ::: "memory");
      }
    }
    EPILOGUE(3);
  }
#undef STAGE
#undef AFRAGS
#undef EPILOGUE
}

// ---------------- fused causal attention (8-wave, 128-row q-tiles) -------
// NEW vs R17: block = 512 threads = 8 waves x 16 q-rows (128 rows), so
// each staged K/V tile feeds 2x the q-rows: staging bytes and barriers
// per q-row halve. Grid 512 = 256 batches x 2 q-tiles = exactly 2 even
// generations at 1 block/CU (LDS 112KB). Ring pattern identical to the
// proven R9 attn; vmcnt counts re-derived for 2-load stages.
__global__ __launch_bounds__(512) void k_attn(
    const u16* __restrict__ qb, const u16* __restrict__ kb,
    const u16* __restrict__ vT, float* __restrict__ out) {
  __shared__ u16 smem[57344];          // 112 KB
  u16* Ring = smem;                    // 3 x 8192 u16 (16KB slots)
  u16* Ps = smem + 24576;              // [128][256] bf16 = 64KB

  const int tid = threadIdx.x;
  const int lane = tid & 63;
  const int w = tid >> 6;              // 0..7
  int bid = blockIdx.x;                // 512
  int wkk = (bid & 7) * 64 + (bid >> 3);
  const int b = wkk >> 1;
  const int qt = wkk & 1;
  const int t0 = qt * 128;
  const int lrow = lane & 15, lhi = lane >> 4;
  const int sx = lrow & 7;
  const int vxor = (lrow >> 1) & 3;
  const int NT = 8 * (qt + 1);         // K tiles (16 rows each): 8 or 16
  const int NTB = 4 * (qt + 1);        // V s-chunks (32 each): 4 or 8
  const int NV = 2 * NTB;              // V tiles (s-chunk x h-half): 8 or 16

  // Q fragments in registers (wave's 16 rows)
  const u16* qrow = qb + ((size_t)(b * 256 + t0 + w * 16 + lrow)) * 512;
  bf16x8 qf[16];
#pragma unroll
  for (int kk = 0; kk < 16; ++kk)
    qf[kk] = *(const bf16x8*)(qrow + kk * 32 + lhi * 8);

  // stage K tile ST (s-rows ST*16..+15) into ring slot ST%3, pre-swizzled
  // 512 threads -> 2 loads/thread
#define STAGE_K(ST) {                                                         \
    _Pragma("unroll")                                                         \
    for (int ld = 0; ld < 2; ++ld) {                                          \
      int gi = ld * 512 + tid;                                                \
      int r_ = gi >> 6, c_ = gi & 63;                                         \
      async16((char*)Ring + ((ST) % 3) * 16384 + (size_t)gi * 16,             \
              kb + ((size_t)(b * 256 + (ST) * 16 + r_)) * 512 +               \
                  ((c_ ^ (r_ & 7)) * 8));                                     \
    } }

  // stage V tile f=(ST,HH): h-rows HH*256..+255, s-cols ST*32..+31
#define STAGE_V(ST, HH) {                                                     \
    _Pragma("unroll")                                                         \
    for (int ld = 0; ld < 2; ++ld) {                                          \
      int gi = ld * 512 + tid;                                                \
      int r_ = gi >> 2, c_ = gi & 3;                                          \
      async16((char*)Ring + (((ST) * 2 + (HH)) % 3) * 16384 + (size_t)gi * 16,\
              vT + (size_t)b * 131072 + ((size_t)((HH) * 256 + r_)) * 256 +   \
                  (ST) * 32 + ((c_ ^ ((r_ >> 1) & 3)) * 8));                  \
    } }

  // ---- phase A: S = Q K^T, ring-pipelined over NT 16-row K tiles ----
  f32x4 sa[16] = {};
  STAGE_K(0); STAGE_K(1);
  asm volatile("s_waitcnt vmcnt(2)" ::: "memory");
  __builtin_amdgcn_s_barrier();
  asm volatile("" ::: "memory");
#pragma unroll
  for (int st = 0; st < 16; ++st) {
    if (st < NT) {
      if (st + 2 < NT) STAGE_K(st + 2);
      const u16* Ksl = Ring + (st % 3) * 8192 + lrow * 512;
      __builtin_amdgcn_s_setprio(1);
#pragma unroll
      for (int kk = 0; kk < 16; ++kk) {
        bf16x8 bf = *(const bf16x8*)(Ksl + ((kk * 4 + lhi) ^ sx) * 8);
        sa[st] = __builtin_amdgcn_mfma_f32_16x16x32_bf16(qf[kk], bf, sa[st], 0, 0, 0);
      }
      __builtin_amdgcn_s_setprio(0);
      if (st + 2 < NT)      asm volatile("s_waitcnt vmcnt(2)" ::: "memory");
      else if (st + 1 < NT) asm volatile("s_waitcnt vmcnt(0)" ::: "memory");
      if (st + 1 < NT) {
        __builtin_amdgcn_s_barrier();
        asm volatile("" ::: "memory");
      }
    }
  }

  // ---- softmax (rows spread over 16 lrow lanes) ----
  // n >= NT: sa stays 0 but s = n*16+lrow > t always (s >= NT*16 > smax),
  // so the causal mask zeroes it.
  const float scale = 0.04472135954999579f;   // 500^-0.5
  float rmax[4] = {-1e30f, -1e30f, -1e30f, -1e30f};
#pragma unroll
  for (int n = 0; n < 16; ++n) {
    int s = n * 16 + lrow;
#pragma unroll
    for (int j = 0; j < 4; ++j) {
      int t = t0 + w * 16 + lhi * 4 + j;
      float v = sa[n][j] * scale;
      if (s > t) v = -1e30f;
      sa[n][j] = v;
      rmax[j] = fmaxf(rmax[j], v);
    }
  }
#pragma unroll
  for (int j = 0; j < 4; ++j)
#pragma unroll
    for (int msk = 1; msk < 16; msk <<= 1)
      rmax[j] = fmaxf(rmax[j], __shfl_xor(rmax[j], msk, 64));
  float rsum[4] = {0.f, 0.f, 0.f, 0.f};
#pragma unroll
  for (int n = 0; n < 16; ++n)
#pragma unroll
    for (int j = 0; j < 4; ++j) {
      float p = __expf(sa[n][j] - rmax[j]);
      sa[n][j] = p;
      rsum[j] += p;
    }
#pragma unroll
  for (int j = 0; j < 4; ++j)
#pragma unroll
    for (int msk = 1; msk < 16; msk <<= 1)
      rsum[j] += __shfl_xor(rsum[j], msk, 64);
  float rinv[4];
#pragma unroll
  for (int j = 0; j < 4; ++j) rinv[j] = 1.0f / rsum[j];

  // write P (bf16) to LDS [128][256], 16B-slot swizzled
#pragma unroll
  for (int n = 0; n < 16; ++n)
#pragma unroll
    for (int j = 0; j < 4; ++j) {
      int s = n * 16 + lrow;
      int trow = w * 16 + lhi * 4 + j;
      int slot = (s >> 3) ^ (trow & 7);
      Ps[trow * 256 + slot * 8 + (s & 7)] = f2bf(sa[n][j] * rinv[j]);
    }

  // realias barrier: all K reads done + P visible before V staging
  __syncthreads();

  // ---- phase B: O = P V, ring-pipelined over NV (s-chunk, h-half) tiles --
  f32x4 o[2][16] = {};
  STAGE_V(0, 0); STAGE_V(0, 1);
  asm volatile("s_waitcnt vmcnt(2)" ::: "memory");
  __builtin_amdgcn_s_barrier();
  asm volatile("" ::: "memory");
#pragma unroll
  for (int st = 0; st < 8; ++st) {
    if (st < NTB) {
#pragma unroll
      for (int hh = 0; hh < 2; ++hh) {
        const int f = st * 2 + hh;
        if (f + 2 < NV) {
          if (hh == 0) STAGE_V(st + 1, 0) else STAGE_V(st + 1, 1);
        }
        bf16x8 pf = *(const bf16x8*)&Ps[(w * 16 + lrow) * 256 + ((st * 4 + lhi) ^ sx) * 8];
        const u16* Vsl = Ring + (f % 3) * 8192;
        __builtin_amdgcn_s_setprio(1);
#pragma unroll
        for (int ni = 0; ni < 16; ++ni) {
          bf16x8 vf = *(const bf16x8*)(Vsl + (ni * 16 + lrow) * 32 + (lhi ^ vxor) * 8);
          o[hh][ni] = __builtin_amdgcn_mfma_f32_16x16x32_bf16(pf, vf, o[hh][ni], 0, 0, 0);
        }
        __builtin_amdgcn_s_setprio(0);
        if (f + 2 < NV)      asm volatile("s_waitcnt vmcnt(2)" ::: "memory");
        else if (f + 1 < NV) asm volatile("s_waitcnt vmcnt(0)" ::: "memory");
        if (f + 1 < NV) {
          __builtin_amdgcn_s_barrier();
          asm volatile("" ::: "memory");
        }
      }
    }
  }
#undef STAGE_K
#undef STAGE_V

  // ---- epilogue ----
  const int tb = t0 + w * 16;
#pragma unroll
  for (int hh = 0; hh < 2; ++hh)
#pragma unroll
    for (int ni = 0; ni < 16; ++ni) {
      int h = hh * 256 + ni * 16 + lrow;
      if (h < 500) {
#pragma unroll
        for (int j = 0; j < 4; ++j) {
          int t = tb + lhi * 4 + j;
          out[((size_t)(b * 256 + t)) * 500 + h] = o[hh][ni][j];
        }
      }
    }
}

extern "C" void kernel_launch(void* const* d_in, const int* in_sizes, int n_in,
                              void* d_out, int out_size, void* d_ws, size_t ws_size,
                              hipStream_t stream) {
  const float* x  = (const float*)d_in[0];
  const float* Wq = (const float*)d_in[1];
  const float* Wk = (const float*)d_in[2];
  const float* Wv = (const float*)d_in[3];
  float* out = (float*)d_out;

  u16* xb = (u16*)d_ws;                 // [65536][512] bf16
  u16* qb = xb + 33554432;              // [65536][512]
  u16* kb = qb + 33554432;              // [65536][512]
  u16* vT = kb + 33554432;              // [256][512][256]
  u16* Wt = vT + 33554432;              // [1536][512]
  float* cospair = (float*)(Wt + 786432); // [256][256]
  float* sinpair = cospair + 65536;       // [256][256]

  k_convert_x<<<16384, 256, 0, stream>>>(x, xb);
  k_convert_w<<<3072, 256, 0, stream>>>(Wq, Wk, Wv, Wt);
  k_tables<<<256, 256, 0, stream>>>(cospair, sinpair);
  k_gemm_qkv<<<1536, 512, 0, stream>>>(xb, Wt, cospair, sinpair, qb, kb, vT);
  k_attn<<<512, 512, 0, stream>>>(qb, kb, vT, out);
}

// Round 19
// 309.585 us; speedup vs baseline: 1.4099x; 1.0099x over previous
//
#include <hip/hip_runtime.h>

typedef unsigned short u16;
typedef __attribute__((ext_vector_type(8))) __bf16 bf16x8;
typedef __attribute__((ext_vector_type(4))) float f32x4;

__device__ __forceinline__ float bf2f(u16 u) {
  union { unsigned int i; float f; } v; v.i = ((unsigned int)u) << 16; return v.f;
}
__device__ __forceinline__ u16 f2bf(float f) {
  union { float f; unsigned int i; } v; v.f = f;
  unsigned int u = v.i;
  return (u16)((u + 0x7fffu + ((u >> 16) & 1u)) >> 16);  // RNE
}
__device__ __forceinline__ void async16(void* lds, const void* g) {
  __builtin_amdgcn_global_load_lds(
      (const __attribute__((address_space(1))) unsigned int*)g,
      (__attribute__((address_space(3))) unsigned int*)lds, 16, 0, 0);
}

// ---------------- conversions ----------------
// 8 elems/thread; float4 loads, 16B stores. Tail c0>=496 scalar.
__global__ void k_convert_x(const float* __restrict__ x, u16* __restrict__ xb) {
  int idx = blockIdx.x * 256 + threadIdx.x;       // 65536*64 threads
  int m = idx >> 6, c0 = (idx & 63) * 8;
  u16 o[8];
  if (c0 < 496) {
    float4 v0 = *(const float4*)(x + (size_t)m * 500 + c0);
    float4 v1 = *(const float4*)(x + (size_t)m * 500 + c0 + 4);
    o[0] = f2bf(v0.x); o[1] = f2bf(v0.y); o[2] = f2bf(v0.z); o[3] = f2bf(v0.w);
    o[4] = f2bf(v1.x); o[5] = f2bf(v1.y); o[6] = f2bf(v1.z); o[7] = f2bf(v1.w);
  } else {
#pragma unroll
    for (int j = 0; j < 8; ++j) {
      int c = c0 + j;
      o[j] = f2bf((c < 500) ? x[(size_t)m * 500 + c] : 0.f);
    }
  }
  *(uint4*)(xb + (size_t)m * 512 + c0) = *(const uint4*)o;
}

// W^T, padded; for q,k the OUTPUT columns are permuted so RoPE pairs are
// adjacent: new col 2p <- old col p, new col 2p+1 <- old col p+250 (p<250).
__global__ void k_convert_w(const float* __restrict__ Wq, const float* __restrict__ Wk,
                            const float* __restrict__ Wv, u16* __restrict__ Wt) {
  int idx = blockIdx.x * 256 + threadIdx.x;       // 3*512*512
  int g = idx >> 18;
  int r = idx & 262143;
  int n = r >> 9, k = r & 511;
  const float* W = (g == 0) ? Wq : (g == 1) ? Wk : Wv;
  int orig = (g == 2) ? n : ((n & 1) ? (n >> 1) + 250 : (n >> 1));
  float v = (n < 500 && k < 500) ? W[(size_t)k * 500 + orig] : 0.f;
  Wt[idx] = f2bf(v);
}

// pair tables: cospair[t][p] = cos(t * freq_p), freq_p = 1e-4^(2*(p/2)/500)
__global__ void k_tables(float* __restrict__ cospair, float* __restrict__ sinpair) {
  int t = blockIdx.x, p = threadIdx.x;
  float c = 0.f, s = 0.f;
  if (p < 250) {
    float ex = (float)(2 * (p >> 1)) / 500.0f;
    float fr = powf(1e-4f, ex);
    float ang = (float)t * fr;
    c = cosf(ang); s = sinf(ang);
  }
  cospair[t * 256 + p] = c;
  sinpair[t * 256 + p] = s;
}

// ---------------- QKV projection GEMM + fused RoPE (8-wave, sub-phased) ---
// Base = R14 verified best (190us, MfmaUtil 22.5%, VGPR 120): 8 waves
// (2M x 4N) on 128M x 128N per M-tile, 4 M-tiles; wave tile 64x32; B in
// registers from L2; A via 4-slot LDS ring, distance-3, counted vmcnt.
// NEW (R19): each K-step split into TWO sub-phases {4 ds_reads -> barrier
// -> setprio(1) 8 MFMA setprio(0) -> barrier} — the m201/HK mechanism:
// waves enter MFMA staggered as their reads land, LDS and MFMA pipes
// overlap across waves instead of running serially in lockstep, and
// setprio finally has a role-split to arbitrate (T5 is null in lockstep,
// +21-25% in phase-split schedules). Ring invariant unchanged (extra
// barriers only add sync points; vmcnt counts only the gload_lds).
// LAUNCH BOUNDS: cap ~= 256/arg2. (512,2)->128 ok; (512,4)->64 spills
// (R10); (256,3)->84 spills (R7). Do not change arg2.
__global__ __launch_bounds__(512, 2) void k_gemm_qkv(
    const u16* __restrict__ xb, const u16* __restrict__ Wt,
    const float* __restrict__ cospair, const float* __restrict__ sinpair,
    u16* __restrict__ qb, u16* __restrict__ kb, u16* __restrict__ vT) {
  __shared__ u16 As[4][128][64];   // 64 KB
  const int tid = threadIdx.x;
  const int lane = tid & 63;
  const int w = tid >> 6;              // 0..7
  const int wm = w >> 2, wn = w & 3;   // 2M x 4N wave grid on 128M x 128N
  const int lrow = lane & 15, lhi = lane >> 4;
  const int sx = lrow & 7;

  int bid = blockIdx.x;
  int wk = (bid & 7) * 192 + (bid >> 3);
  int mg = wk / 12;
  int j12 = wk - mg * 12;
  int g = j12 >> 2, bni = j12 & 3;
  const int bn = bni << 7;             // 0,128,256,384
  const int m0 = mg << 9;              // 512 rows per block

  const u16* Ab = xb + (size_t)m0 * 512;

  bf16x8 breg[8][2][2];
  {
    const u16* Bl = Wt + ((size_t)(g * 512 + bn + wn * 32) + lrow) * 512 + lhi * 8;
#pragma unroll
    for (int t = 0; t < 8; ++t)
#pragma unroll
      for (int ni = 0; ni < 2; ++ni)
#pragma unroll
        for (int kk2 = 0; kk2 < 2; ++kk2)
          breg[t][ni][kk2] =
              *(const bf16x8*)(Bl + (size_t)ni * 16 * 512 + t * 64 + kk2 * 32);
  }

#define STAGE(S) { int mt_ = (S) >> 3, t_ = (S) & 7, buf_ = (S) & 3;          \
    _Pragma("unroll")                                                         \
    for (int ld = 0; ld < 2; ++ld) {                                          \
      int gi = ld * 512 + tid;                                                \
      int r_ = gi >> 3, c_ = gi & 7;                                          \
      async16((char*)As + buf_ * 16384 + (size_t)gi * 16,                     \
              Ab + ((size_t)(mt_ * 128 + r_)) * 512 + t_ * 64 +               \
                  ((c_ ^ (r_ & 7)) * 8));                                     \
    } }

  // one sub-phase: 4 ds_reads (half-K frags) -> barrier -> 8 MFMA
#define SUBPHASE(T, KK2) {                                                    \
    const u16* Asl = (const u16*)As + ((T) & 3) * 8192;                       \
    bf16x8 a[4];                                                              \
    _Pragma("unroll")                                                         \
    for (int mi = 0; mi < 4; ++mi)                                            \
      a[mi] = *(const bf16x8*)(Asl + (wm * 64 + mi * 16 + lrow) * 64 +        \
                               ((((KK2) * 4 + lhi) ^ sx) * 8));               \
    __builtin_amdgcn_s_barrier();                                             \
    __builtin_amdgcn_s_setprio(1);                                            \
    _Pragma("unroll")                                                         \
    for (int mi = 0; mi < 4; ++mi)                                            \
      _Pragma("unroll")                                                       \
      for (int ni = 0; ni < 2; ++ni)                                          \
        acc[mi][ni] = __builtin_amdgcn_mfma_f32_16x16x32_bf16(                \
            a[mi], breg[T][ni][KK2], acc[mi][ni], 0, 0, 0);                   \
    __builtin_amdgcn_s_setprio(0);                                            \
  }

#define EPILOGUE(MT) {                                                        \
    int mb = m0 + (MT) * 128;                                                 \
    if (g < 2) {                                                              \
      u16* dst = (g == 0) ? qb : kb;                                          \
      _Pragma("unroll")                                                       \
      for (int mi = 0; mi < 4; ++mi)                                          \
        _Pragma("unroll")                                                     \
        for (int ni = 0; ni < 2; ++ni) {                                      \
          int n = bn + wn * 32 + ni * 16 + lrow;                              \
          int p = n >> 1;                                                     \
          _Pragma("unroll")                                                   \
          for (int jj = 0; jj < 4; ++jj) {                                    \
            int m = mb + wm * 64 + mi * 16 + lhi * 4 + jj;                    \
            float v = acc[mi][ni][jj];                                        \
            float o = __shfl_xor(v, 1, 64);                                   \
            int ti = (m & 255) * 256 + p;                                     \
            float c = cospair[ti], s = sinpair[ti];                           \
            float r = (n & 1) ? (o * s + v * c) : (v * c - o * s);            \
            dst[(size_t)m * 512 + n] = f2bf(r);                               \
          }                                                                   \
        }                                                                     \
    } else {                                                                  \
      _Pragma("unroll")                                                       \
      for (int mi = 0; mi < 4; ++mi)                                          \
        _Pragma("unroll")                                                     \
        for (int ni = 0; ni < 2; ++ni) {                                      \
          int n = bn + wn * 32 + ni * 16 + lrow;                              \
          _Pragma("unroll")                                                   \
          for (int jj = 0; jj < 4; ++jj) {                                    \
            int m = mb + wm * 64 + mi * 16 + lhi * 4 + jj;                    \
            vT[(size_t)(m >> 8) * 131072 + (size_t)n * 256 + (m & 255)] =     \
                f2bf(acc[mi][ni][jj]);                                        \
          }                                                                   \
        }                                                                     \
    } }

  STAGE(0); STAGE(1); STAGE(2);
  asm volatile("s_waitcnt vmcnt(4)" ::: "memory");   // tile 0 resident
  __builtin_amdgcn_s_barrier();
  asm volatile("" ::: "memory");

  for (int mt = 0; mt < 3; ++mt) {
    f32x4 acc[4][2] = {};
#pragma unroll
    for (int t = 0; t < 8; ++t) {
      STAGE(mt * 8 + t + 3);
      SUBPHASE(t, 0)
      __builtin_amdgcn_s_barrier();
      SUBPHASE(t, 1)
      asm volatile("s_waitcnt vmcnt(4)" ::: "memory");
      __builtin_amdgcn_s_barrier();
      asm volatile("" ::: "memory");
    }
    EPILOGUE(mt);
  }
  {                                                  // mt = 3 (tail)
    f32x4 acc[4][2] = {};
#pragma unroll
    for (int t = 0; t < 8; ++t) {
      if (t < 5) STAGE(27 + t);
      SUBPHASE(t, 0)
      __builtin_amdgcn_s_barrier();
      SUBPHASE(t, 1)
      if (t < 5)       asm volatile("s_waitcnt vmcnt(4)" ::: "memory");
      else if (t == 5) asm volatile("s_waitcnt vmcnt(2)" ::: "memory");
      else if (t == 6) asm volatile("s_waitcnt vmcnt(0)" ::: "memory");
      if (t < 7) {
        __builtin_amdgcn_s_barrier();
        asm volatile("" ::: "memory");
      }
    }
    EPILOGUE(3);
  }
#undef STAGE
#undef SUBPHASE
#undef EPILOGUE
}

// ---------------- fused causal attention (8-wave, 128-row q-tiles) -------
// R18 verified: block = 512 threads = 8 waves x 16 q-rows (128 rows);
// staged K/V tiles feed 2x the q-rows vs 4-wave version. Grid 512 at
// 1 block/CU (LDS 112KB). 3-slot ring, distance-2, counted vmcnt.
__global__ __launch_bounds__(512) void k_attn(
    const u16* __restrict__ qb, const u16* __restrict__ kb,
    const u16* __restrict__ vT, float* __restrict__ out) {
  __shared__ u16 smem[57344];          // 112 KB
  u16* Ring = smem;                    // 3 x 8192 u16 (16KB slots)
  u16* Ps = smem + 24576;              // [128][256] bf16 = 64KB

  const int tid = threadIdx.x;
  const int lane = tid & 63;
  const int w = tid >> 6;              // 0..7
  int bid = blockIdx.x;                // 512
  int wkk = (bid & 7) * 64 + (bid >> 3);
  const int b = wkk >> 1;
  const int qt = wkk & 1;
  const int t0 = qt * 128;
  const int lrow = lane & 15, lhi = lane >> 4;
  const int sx = lrow & 7;
  const int vxor = (lrow >> 1) & 3;
  const int NT = 8 * (qt + 1);         // K tiles (16 rows each): 8 or 16
  const int NTB = 4 * (qt + 1);        // V s-chunks (32 each): 4 or 8
  const int NV = 2 * NTB;              // V tiles (s-chunk x h-half): 8 or 16

  // Q fragments in registers (wave's 16 rows)
  const u16* qrow = qb + ((size_t)(b * 256 + t0 + w * 16 + lrow)) * 512;
  bf16x8 qf[16];
#pragma unroll
  for (int kk = 0; kk < 16; ++kk)
    qf[kk] = *(const bf16x8*)(qrow + kk * 32 + lhi * 8);

  // stage K tile ST (s-rows ST*16..+15) into ring slot ST%3, pre-swizzled
#define STAGE_K(ST) {                                                         \
    _Pragma("unroll")                                                         \
    for (int ld = 0; ld < 2; ++ld) {                                          \
      int gi = ld * 512 + tid;                                                \
      int r_ = gi >> 6, c_ = gi & 63;                                         \
      async16((char*)Ring + ((ST) % 3) * 16384 + (size_t)gi * 16,             \
              kb + ((size_t)(b * 256 + (ST) * 16 + r_)) * 512 +               \
                  ((c_ ^ (r_ & 7)) * 8));                                     \
    } }

  // stage V tile f=(ST,HH): h-rows HH*256..+255, s-cols ST*32..+31
#define STAGE_V(ST, HH) {                                                     \
    _Pragma("unroll")                                                         \
    for (int ld = 0; ld < 2; ++ld) {                                          \
      int gi = ld * 512 + tid;                                                \
      int r_ = gi >> 2, c_ = gi & 3;                                          \
      async16((char*)Ring + (((ST) * 2 + (HH)) % 3) * 16384 + (size_t)gi * 16,\
              vT + (size_t)b * 131072 + ((size_t)((HH) * 256 + r_)) * 256 +   \
                  (ST) * 32 + ((c_ ^ ((r_ >> 1) & 3)) * 8));                  \
    } }

  // ---- phase A: S = Q K^T, ring-pipelined over NT 16-row K tiles ----
  f32x4 sa[16] = {};
  STAGE_K(0); STAGE_K(1);
  asm volatile("s_waitcnt vmcnt(2)" ::: "memory");
  __builtin_amdgcn_s_barrier();
  asm volatile("" ::: "memory");
#pragma unroll
  for (int st = 0; st < 16; ++st) {
    if (st < NT) {
      if (st + 2 < NT) STAGE_K(st + 2);
      const u16* Ksl = Ring + (st % 3) * 8192 + lrow * 512;
      __builtin_amdgcn_s_setprio(1);
#pragma unroll
      for (int kk = 0; kk < 16; ++kk) {
        bf16x8 bf = *(const bf16x8*)(Ksl + ((kk * 4 + lhi) ^ sx) * 8);
        sa[st] = __builtin_amdgcn_mfma_f32_16x16x32_bf16(qf[kk], bf, sa[st], 0, 0, 0);
      }
      __builtin_amdgcn_s_setprio(0);
      if (st + 2 < NT)      asm volatile("s_waitcnt vmcnt(2)" ::: "memory");
      else if (st + 1 < NT) asm volatile("s_waitcnt vmcnt(0)" ::: "memory");
      if (st + 1 < NT) {
        __builtin_amdgcn_s_barrier();
        asm volatile("" ::: "memory");
      }
    }
  }

  // ---- softmax (rows spread over 16 lrow lanes) ----
  const float scale = 0.04472135954999579f;   // 500^-0.5
  float rmax[4] = {-1e30f, -1e30f, -1e30f, -1e30f};
#pragma unroll
  for (int n = 0; n < 16; ++n) {
    int s = n * 16 + lrow;
#pragma unroll
    for (int j = 0; j < 4; ++j) {
      int t = t0 + w * 16 + lhi * 4 + j;
      float v = sa[n][j] * scale;
      if (s > t) v = -1e30f;
      sa[n][j] = v;
      rmax[j] = fmaxf(rmax[j], v);
    }
  }
#pragma unroll
  for (int j = 0; j < 4; ++j)
#pragma unroll
    for (int msk = 1; msk < 16; msk <<= 1)
      rmax[j] = fmaxf(rmax[j], __shfl_xor(rmax[j], msk, 64));
  float rsum[4] = {0.f, 0.f, 0.f, 0.f};
#pragma unroll
  for (int n = 0; n < 16; ++n)
#pragma unroll
    for (int j = 0; j < 4; ++j) {
      float p = __expf(sa[n][j] - rmax[j]);
      sa[n][j] = p;
      rsum[j] += p;
    }
#pragma unroll
  for (int j = 0; j < 4; ++j)
#pragma unroll
    for (int msk = 1; msk < 16; msk <<= 1)
      rsum[j] += __shfl_xor(rsum[j], msk, 64);
  float rinv[4];
#pragma unroll
  for (int j = 0; j < 4; ++j) rinv[j] = 1.0f / rsum[j];

  // write P (bf16) to LDS [128][256], 16B-slot swizzled
#pragma unroll
  for (int n = 0; n < 16; ++n)
#pragma unroll
    for (int j = 0; j < 4; ++j) {
      int s = n * 16 + lrow;
      int trow = w * 16 + lhi * 4 + j;
      int slot = (s >> 3) ^ (trow & 7);
      Ps[trow * 256 + slot * 8 + (s & 7)] = f2bf(sa[n][j] * rinv[j]);
    }

  // realias barrier: all K reads done + P visible before V staging
  __syncthreads();

  // ---- phase B: O = P V, ring-pipelined over NV (s-chunk, h-half) tiles --
  f32x4 o[2][16] = {};
  STAGE_V(0, 0); STAGE_V(0, 1);
  asm volatile("s_waitcnt vmcnt(2)" ::: "memory");
  __builtin_amdgcn_s_barrier();
  asm volatile("" ::: "memory");
#pragma unroll
  for (int st = 0; st < 8; ++st) {
    if (st < NTB) {
#pragma unroll
      for (int hh = 0; hh < 2; ++hh) {
        const int f = st * 2 + hh;
        if (f + 2 < NV) {
          if (hh == 0) STAGE_V(st + 1, 0) else STAGE_V(st + 1, 1);
        }
        bf16x8 pf = *(const bf16x8*)&Ps[(w * 16 + lrow) * 256 + ((st * 4 + lhi) ^ sx) * 8];
        const u16* Vsl = Ring + (f % 3) * 8192;
        __builtin_amdgcn_s_setprio(1);
#pragma unroll
        for (int ni = 0; ni < 16; ++ni) {
          bf16x8 vf = *(const bf16x8*)(Vsl + (ni * 16 + lrow) * 32 + (lhi ^ vxor) * 8);
          o[hh][ni] = __builtin_amdgcn_mfma_f32_16x16x32_bf16(pf, vf, o[hh][ni], 0, 0, 0);
        }
        __builtin_amdgcn_s_setprio(0);
        if (f + 2 < NV)      asm volatile("s_waitcnt vmcnt(2)" ::: "memory");
        else if (f + 1 < NV) asm volatile("s_waitcnt vmcnt(0)" ::: "memory");
        if (f + 1 < NV) {
          __builtin_amdgcn_s_barrier();
          asm volatile("" ::: "memory");
        }
      }
    }
  }
#undef STAGE_K
#undef STAGE_V

  // ---- epilogue ----
  const int tb = t0 + w * 16;
#pragma unroll
  for (int hh = 0; hh < 2; ++hh)
#pragma unroll
    for (int ni = 0; ni < 16; ++ni) {
      int h = hh * 256 + ni * 16 + lrow;
      if (h < 500) {
#pragma unroll
        for (int j = 0; j < 4; ++j) {
          int t = tb + lhi * 4 + j;
          out[((size_t)(b * 256 + t)) * 500 + h] = o[hh][ni][j];
        }
      }
    }
}

extern "C" void kernel_launch(void* const* d_in, const int* in_sizes, int n_in,
                              void* d_out, int out_size, void* d_ws, size_t ws_size,
                              hipStream_t stream) {
  const float* x  = (const float*)d_in[0];
  const float* Wq = (const float*)d_in[1];
  const float* Wk = (const float*)d_in[2];
  const float* Wv = (const float*)d_in[3];
  float* out = (float*)d_out;

  u16* xb = (u16*)d_ws;                 // [65536][512] bf16
  u16* qb = xb + 33554432;              // [65536][512]
  u16* kb = qb + 33554432;              // [65536][512]
  u16* vT = kb + 33554432;              // [256][512][256]
  u16* Wt = vT + 33554432;              // [1536][512]
  float* cospair = (float*)(Wt + 786432); // [256][256]
  float* sinpair = cospair + 65536;       // [256][256]

  k_convert_x<<<16384, 256, 0, stream>>>(x, xb);
  k_convert_w<<<3072, 256, 0, stream>>>(Wq, Wk, Wv, Wt);
  k_tables<<<256, 256, 0, stream>>>(cospair, sinpair);
  k_gemm_qkv<<<1536, 512, 0, stream>>>(xb, Wt, cospair, sinpair, qb, kb, vT);
  k_attn<<<512, 512, 0, stream>>>(qb, kb, vT, out);
}

// Round 20
// 300.494 us; speedup vs baseline: 1.4525x; 1.0303x over previous
//
#include <hip/hip_runtime.h>

typedef unsigned short u16;
typedef __attribute__((ext_vector_type(8))) __bf16 bf16x8;
typedef __attribute__((ext_vector_type(4))) float f32x4;

__device__ __forceinline__ float bf2f(u16 u) {
  union { unsigned int i; float f; } v; v.i = ((unsigned int)u) << 16; return v.f;
}
__device__ __forceinline__ u16 f2bf(float f) {
  union { float f; unsigned int i; } v; v.f = f;
  unsigned int u = v.i;
  return (u16)((u + 0x7fffu + ((u >> 16) & 1u)) >> 16);  // RNE
}
__device__ __forceinline__ void async16(void* lds, const void* g) {
  __builtin_amdgcn_global_load_lds(
      (const __attribute__((address_space(1))) unsigned int*)g,
      (__attribute__((address_space(3))) unsigned int*)lds, 16, 0, 0);
}

// ---------------- fused prep: convert_x | convert_w | tables ----------------
// One dispatch, branch by block range (block-uniform): saves 2 launch
// overheads + the serial tails of the two tiny kernels.
__global__ void k_prep(const float* __restrict__ x, const float* __restrict__ Wq,
                       const float* __restrict__ Wk, const float* __restrict__ Wv,
                       u16* __restrict__ xb, u16* __restrict__ Wt,
                       float* __restrict__ cospair, float* __restrict__ sinpair) {
  int blk = blockIdx.x;
  if (blk < 16384) {
    // convert_x: 8 elems/thread; float4 loads, 16B stores; tail scalar.
    int idx = blk * 256 + threadIdx.x;
    int m = idx >> 6, c0 = (idx & 63) * 8;
    u16 o[8];
    if (c0 < 496) {
      float4 v0 = *(const float4*)(x + (size_t)m * 500 + c0);
      float4 v1 = *(const float4*)(x + (size_t)m * 500 + c0 + 4);
      o[0] = f2bf(v0.x); o[1] = f2bf(v0.y); o[2] = f2bf(v0.z); o[3] = f2bf(v0.w);
      o[4] = f2bf(v1.x); o[5] = f2bf(v1.y); o[6] = f2bf(v1.z); o[7] = f2bf(v1.w);
    } else {
#pragma unroll
      for (int j = 0; j < 8; ++j) {
        int c = c0 + j;
        o[j] = f2bf((c < 500) ? x[(size_t)m * 500 + c] : 0.f);
      }
    }
    *(uint4*)(xb + (size_t)m * 512 + c0) = *(const uint4*)o;
  } else if (blk < 16384 + 3072) {
    // convert_w: W^T, padded; q/k output columns permuted so RoPE pairs
    // are adjacent (new 2p <- old p, new 2p+1 <- old p+250). Dot products
    // over h are permutation-invariant, so wei is unchanged.
    int idx = (blk - 16384) * 256 + threadIdx.x;   // 3*512*512
    int g = idx >> 18;
    int r = idx & 262143;
    int n = r >> 9, k = r & 511;
    const float* W = (g == 0) ? Wq : (g == 1) ? Wk : Wv;
    int orig = (g == 2) ? n : ((n & 1) ? (n >> 1) + 250 : (n >> 1));
    float v = (n < 500 && k < 500) ? W[(size_t)k * 500 + orig] : 0.f;
    Wt[idx] = f2bf(v);
  } else {
    // pair tables: cospair[t][p] = cos(t * freq_p), freq_p = 1e-4^(2*(p/2)/500)
    int t = blk - 16384 - 3072, p = threadIdx.x;
    float c = 0.f, s = 0.f;
    if (p < 250) {
      float ex = (float)(2 * (p >> 1)) / 500.0f;
      float fr = powf(1e-4f, ex);
      float ang = (float)t * fr;
      c = cosf(ang); s = sinf(ang);
    }
    cospair[t * 256 + p] = c;
    sinpair[t * 256 + p] = s;
  }
}

// ---------------- QKV projection GEMM + fused RoPE (8-wave, R14 config) ---
// VERIFIED BEST (190-193us, MfmaUtil 22.5%, VGPR 120). 8 waves (2M x 4N)
// on 128M x 128N per M-tile, 4 M-tiles (512 rows); wave tile 64x32; B in
// registers/remat from L2; A via 4-slot LDS ring (64 KB), distance-3,
// counted vmcnt(4)/(2)/(0) — loads stay in flight across barriers (T3/T4).
// STRUCTURAL CEILING (R11-R19, 8 experiments all neutral/negative):
//   barrier-halving (R12) neutral; B-dbuf+fences (R13) -60%; B-in-LDS
//   dist-1 (R15) -21%; 64x64 tile (R16) -59%; kk2 sub-phases (R19)
//   neutral. The missing lever vs m201 is the fine per-phase
//   ds_read||G-load||MFMA interleave (m196), not reproducible from prose
//   here. Do not re-roll schedule variants on this skeleton.
// LAUNCH BOUNDS: cap ~= 256/arg2. (512,2)->128 ok; (512,4)->64 spills
// (R10); (256,3)->84 spills (R7). Do not change arg2.
__global__ __launch_bounds__(512, 2) void k_gemm_qkv(
    const u16* __restrict__ xb, const u16* __restrict__ Wt,
    const float* __restrict__ cospair, const float* __restrict__ sinpair,
    u16* __restrict__ qb, u16* __restrict__ kb, u16* __restrict__ vT) {
  __shared__ u16 As[4][128][64];   // 64 KB
  const int tid = threadIdx.x;
  const int lane = tid & 63;
  const int w = tid >> 6;              // 0..7
  const int wm = w >> 2, wn = w & 3;   // 2M x 4N wave grid on 128M x 128N
  const int lrow = lane & 15, lhi = lane >> 4;
  const int sx = lrow & 7;

  int bid = blockIdx.x;
  int wk = (bid & 7) * 192 + (bid >> 3);
  int mg = wk / 12;
  int j12 = wk - mg * 12;
  int g = j12 >> 2, bni = j12 & 3;
  const int bn = bni << 7;             // 0,128,256,384
  const int m0 = mg << 9;              // 512 rows per block

  const u16* Ab = xb + (size_t)m0 * 512;

  bf16x8 breg[8][2][2];
  {
    const u16* Bl = Wt + ((size_t)(g * 512 + bn + wn * 32) + lrow) * 512 + lhi * 8;
#pragma unroll
    for (int t = 0; t < 8; ++t)
#pragma unroll
      for (int ni = 0; ni < 2; ++ni)
#pragma unroll
        for (int kk2 = 0; kk2 < 2; ++kk2)
          breg[t][ni][kk2] =
              *(const bf16x8*)(Bl + (size_t)ni * 16 * 512 + t * 64 + kk2 * 32);
  }

#define STAGE(S) { int mt_ = (S) >> 3, t_ = (S) & 7, buf_ = (S) & 3;          \
    _Pragma("unroll")                                                         \
    for (int ld = 0; ld < 2; ++ld) {                                          \
      int gi = ld * 512 + tid;                                                \
      int r_ = gi >> 3, c_ = gi & 7;                                          \
      async16((char*)As + buf_ * 16384 + (size_t)gi * 16,                     \
              Ab + ((size_t)(mt_ * 128 + r_)) * 512 + t_ * 64 +               \
                  ((c_ ^ (r_ & 7)) * 8));                                     \
    } }

#define AFRAGS(S)                                                             \
    const u16* Asl = (const u16*)As + ((S) & 3) * 8192;                       \
    bf16x8 a[4][2];                                                           \
    _Pragma("unroll")                                                         \
    for (int mi = 0; mi < 4; ++mi)                                            \
      _Pragma("unroll")                                                       \
      for (int kk2 = 0; kk2 < 2; ++kk2)                                       \
        a[mi][kk2] = *(const bf16x8*)(Asl + (wm * 64 + mi * 16 + lrow) * 64 + \
                                      (((kk2 * 4 + lhi) ^ sx) * 8));

#define EPILOGUE(MT) {                                                        \
    int mb = m0 + (MT) * 128;                                                 \
    if (g < 2) {                                                              \
      u16* dst = (g == 0) ? qb : kb;                                          \
      _Pragma("unroll")                                                       \
      for (int mi = 0; mi < 4; ++mi)                                          \
        _Pragma("unroll")                                                     \
        for (int ni = 0; ni < 2; ++ni) {                                      \
          int n = bn + wn * 32 + ni * 16 + lrow;                              \
          int p = n >> 1;                                                     \
          _Pragma("unroll")                                                   \
          for (int jj = 0; jj < 4; ++jj) {                                    \
            int m = mb + wm * 64 + mi * 16 + lhi * 4 + jj;                    \
            float v = acc[mi][ni][jj];                                        \
            float o = __shfl_xor(v, 1, 64);                                   \
            int ti = (m & 255) * 256 + p;                                     \
            float c = cospair[ti], s = sinpair[ti];                           \
            float r = (n & 1) ? (o * s + v * c) : (v * c - o * s);            \
            dst[(size_t)m * 512 + n] = f2bf(r);                               \
          }                                                                   \
        }                                                                     \
    } else {                                                                  \
      _Pragma("unroll")                                                       \
      for (int mi = 0; mi < 4; ++mi)                                          \
        _Pragma("unroll")                                                     \
        for (int ni = 0; ni < 2; ++ni) {                                      \
          int n = bn + wn * 32 + ni * 16 + lrow;                              \
          _Pragma("unroll")                                                   \
          for (int jj = 0; jj < 4; ++jj) {                                    \
            int m = mb + wm * 64 + mi * 16 + lhi * 4 + jj;                    \
            vT[(size_t)(m >> 8) * 131072 + (size_t)n * 256 + (m & 255)] =     \
                f2bf(acc[mi][ni][jj]);                                        \
          }                                                                   \
        }                                                                     \
    } }

  STAGE(0); STAGE(1); STAGE(2);
  asm volatile("s_waitcnt vmcnt(4)" ::: "memory");   // tile 0 resident
  __builtin_amdgcn_s_barrier();
  asm volatile("" ::: "memory");

  for (int mt = 0; mt < 3; ++mt) {
    f32x4 acc[4][2] = {};
#pragma unroll
    for (int t = 0; t < 8; ++t) {
      STAGE(mt * 8 + t + 3);
      AFRAGS(t);
      __builtin_amdgcn_s_setprio(1);
#pragma unroll
      for (int kk2 = 0; kk2 < 2; ++kk2)
#pragma unroll
        for (int mi = 0; mi < 4; ++mi)
#pragma unroll
          for (int ni = 0; ni < 2; ++ni)
            acc[mi][ni] = __builtin_amdgcn_mfma_f32_16x16x32_bf16(
                a[mi][kk2], breg[t][ni][kk2], acc[mi][ni], 0, 0, 0);
      __builtin_amdgcn_s_setprio(0);
      asm volatile("s_waitcnt vmcnt(4)" ::: "memory");
      __builtin_amdgcn_s_barrier();
      asm volatile("" ::: "memory");
    }
    EPILOGUE(mt);
  }
  {                                                  // mt = 3 (tail)
    f32x4 acc[4][2] = {};
#pragma unroll
    for (int t = 0; t < 8; ++t) {
      if (t < 5) STAGE(27 + t);
      AFRAGS(t);
      __builtin_amdgcn_s_setprio(1);
#pragma unroll
      for (int kk2 = 0; kk2 < 2; ++kk2)
#pragma unroll
        for (int mi = 0; mi < 4; ++mi)
#pragma unroll
          for (int ni = 0; ni < 2; ++ni)
            acc[mi][ni] = __builtin_amdgcn_mfma_f32_16x16x32_bf16(
                a[mi][kk2], breg[t][ni][kk2], acc[mi][ni], 0, 0, 0);
      __builtin_amdgcn_s_setprio(0);
      if (t < 5)       asm volatile("s_waitcnt vmcnt(4)" ::: "memory");
      else if (t == 5) asm volatile("s_waitcnt vmcnt(2)" ::: "memory");
      else if (t == 6) asm volatile("s_waitcnt vmcnt(0)" ::: "memory");
      if (t < 7) {
        __builtin_amdgcn_s_barrier();
        asm volatile("" ::: "memory");
      }
    }
    EPILOGUE(3);
  }
#undef STAGE
#undef AFRAGS
#undef EPILOGUE
}

// ---------------- fused causal attention (8-wave, 128-row q-tiles) -------
// R18 verified (~90us): block = 512 threads = 8 waves x 16 q-rows (128
// rows); each staged K/V tile feeds 2x the q-rows vs the 4-wave version.
// Grid 512 at 1 block/CU (LDS 112KB). 3-slot ring, distance-2, counted
// vmcnt(2)/(0).
__global__ __launch_bounds__(512) void k_attn(
    const u16* __restrict__ qb, const u16* __restrict__ kb,
    const u16* __restrict__ vT, float* __restrict__ out) {
  __shared__ u16 smem[57344];          // 112 KB
  u16* Ring = smem;                    // 3 x 8192 u16 (16KB slots)
  u16* Ps = smem + 24576;              // [128][256] bf16 = 64KB

  const int tid = threadIdx.x;
  const int lane = tid & 63;
  const int w = tid >> 6;              // 0..7
  int bid = blockIdx.x;                // 512
  int wkk = (bid & 7) * 64 + (bid >> 3);
  const int b = wkk >> 1;
  const int qt = wkk & 1;
  const int t0 = qt * 128;
  const int lrow = lane & 15, lhi = lane >> 4;
  const int sx = lrow & 7;
  const int vxor = (lrow >> 1) & 3;
  const int NT = 8 * (qt + 1);         // K tiles (16 rows each): 8 or 16
  const int NTB = 4 * (qt + 1);        // V s-chunks (32 each): 4 or 8
  const int NV = 2 * NTB;              // V tiles (s-chunk x h-half): 8 or 16

  // Q fragments in registers (wave's 16 rows)
  const u16* qrow = qb + ((size_t)(b * 256 + t0 + w * 16 + lrow)) * 512;
  bf16x8 qf[16];
#pragma unroll
  for (int kk = 0; kk < 16; ++kk)
    qf[kk] = *(const bf16x8*)(qrow + kk * 32 + lhi * 8);

#define STAGE_K(ST) {                                                         \
    _Pragma("unroll")                                                         \
    for (int ld = 0; ld < 2; ++ld) {                                          \
      int gi = ld * 512 + tid;                                                \
      int r_ = gi >> 6, c_ = gi & 63;                                         \
      async16((char*)Ring + ((ST) % 3) * 16384 + (size_t)gi * 16,             \
              kb + ((size_t)(b * 256 + (ST) * 16 + r_)) * 512 +               \
                  ((c_ ^ (r_ & 7)) * 8));                                     \
    } }

#define STAGE_V(ST, HH) {                                                     \
    _Pragma("unroll")                                                         \
    for (int ld = 0; ld < 2; ++ld) {                                          \
      int gi = ld * 512 + tid;                                                \
      int r_ = gi >> 2, c_ = gi & 3;                                          \
      async16((char*)Ring + (((ST) * 2 + (HH)) % 3) * 16384 + (size_t)gi * 16,\
              vT + (size_t)b * 131072 + ((size_t)((HH) * 256 + r_)) * 256 +   \
                  (ST) * 32 + ((c_ ^ ((r_ >> 1) & 3)) * 8));                  \
    } }

  // ---- phase A: S = Q K^T, ring-pipelined over NT 16-row K tiles ----
  f32x4 sa[16] = {};
  STAGE_K(0); STAGE_K(1);
  asm volatile("s_waitcnt vmcnt(2)" ::: "memory");
  __builtin_amdgcn_s_barrier();
  asm volatile("" ::: "memory");
#pragma unroll
  for (int st = 0; st < 16; ++st) {
    if (st < NT) {
      if (st + 2 < NT) STAGE_K(st + 2);
      const u16* Ksl = Ring + (st % 3) * 8192 + lrow * 512;
      __builtin_amdgcn_s_setprio(1);
#pragma unroll
      for (int kk = 0; kk < 16; ++kk) {
        bf16x8 bf = *(const bf16x8*)(Ksl + ((kk * 4 + lhi) ^ sx) * 8);
        sa[st] = __builtin_amdgcn_mfma_f32_16x16x32_bf16(qf[kk], bf, sa[st], 0, 0, 0);
      }
      __builtin_amdgcn_s_setprio(0);
      if (st + 2 < NT)      asm volatile("s_waitcnt vmcnt(2)" ::: "memory");
      else if (st + 1 < NT) asm volatile("s_waitcnt vmcnt(0)" ::: "memory");
      if (st + 1 < NT) {
        __builtin_amdgcn_s_barrier();
        asm volatile("" ::: "memory");
      }
    }
  }

  // ---- softmax (rows spread over 16 lrow lanes) ----
  const float scale = 0.04472135954999579f;   // 500^-0.5
  float rmax[4] = {-1e30f, -1e30f, -1e30f, -1e30f};
#pragma unroll
  for (int n = 0; n < 16; ++n) {
    int s = n * 16 + lrow;
#pragma unroll
    for (int j = 0; j < 4; ++j) {
      int t = t0 + w * 16 + lhi * 4 + j;
      float v = sa[n][j] * scale;
      if (s > t) v = -1e30f;
      sa[n][j] = v;
      rmax[j] = fmaxf(rmax[j], v);
    }
  }
#pragma unroll
  for (int j = 0; j < 4; ++j)
#pragma unroll
    for (int msk = 1; msk < 16; msk <<= 1)
      rmax[j] = fmaxf(rmax[j], __shfl_xor(rmax[j], msk, 64));
  float rsum[4] = {0.f, 0.f, 0.f, 0.f};
#pragma unroll
  for (int n = 0; n < 16; ++n)
#pragma unroll
    for (int j = 0; j < 4; ++j) {
      float p = __expf(sa[n][j] - rmax[j]);
      sa[n][j] = p;
      rsum[j] += p;
    }
#pragma unroll
  for (int j = 0; j < 4; ++j)
#pragma unroll
    for (int msk = 1; msk < 16; msk <<= 1)
      rsum[j] += __shfl_xor(rsum[j], msk, 64);
  float rinv[4];
#pragma unroll
  for (int j = 0; j < 4; ++j) rinv[j] = 1.0f / rsum[j];

  // write P (bf16) to LDS [128][256], 16B-slot swizzled
#pragma unroll
  for (int n = 0; n < 16; ++n)
#pragma unroll
    for (int j = 0; j < 4; ++j) {
      int s = n * 16 + lrow;
      int trow = w * 16 + lhi * 4 + j;
      int slot = (s >> 3) ^ (trow & 7);
      Ps[trow * 256 + slot * 8 + (s & 7)] = f2bf(sa[n][j] * rinv[j]);
    }

  // realias barrier: all K reads done + P visible before V staging
  __syncthreads();

  // ---- phase B: O = P V, ring-pipelined over NV (s-chunk, h-half) tiles --
  f32x4 o[2][16] = {};
  STAGE_V(0, 0); STAGE_V(0, 1);
  asm volatile("s_waitcnt vmcnt(2)" ::: "memory");
  __builtin_amdgcn_s_barrier();
  asm volatile("" ::: "memory");
#pragma unroll
  for (int st = 0; st < 8; ++st) {
    if (st < NTB) {
#pragma unroll
      for (int hh = 0; hh < 2; ++hh) {
        const int f = st * 2 + hh;
        if (f + 2 < NV) {
          if (hh == 0) STAGE_V(st + 1, 0) else STAGE_V(st + 1, 1);
        }
        bf16x8 pf = *(const bf16x8*)&Ps[(w * 16 + lrow) * 256 + ((st * 4 + lhi) ^ sx) * 8];
        const u16* Vsl = Ring + (f % 3) * 8192;
        __builtin_amdgcn_s_setprio(1);
#pragma unroll
        for (int ni = 0; ni < 16; ++ni) {
          bf16x8 vf = *(const bf16x8*)(Vsl + (ni * 16 + lrow) * 32 + (lhi ^ vxor) * 8);
          o[hh][ni] = __builtin_amdgcn_mfma_f32_16x16x32_bf16(pf, vf, o[hh][ni], 0, 0, 0);
        }
        __builtin_amdgcn_s_setprio(0);
        if (f + 2 < NV)      asm volatile("s_waitcnt vmcnt(2)" ::: "memory");
        else if (f + 1 < NV) asm volatile("s_waitcnt vmcnt(0)" ::: "memory");
        if (f + 1 < NV) {
          __builtin_amdgcn_s_barrier();
          asm volatile("" ::: "memory");
        }
      }
    }
  }
#undef STAGE_K
#undef STAGE_V

  // ---- epilogue ----
  const int tb = t0 + w * 16;
#pragma unroll
  for (int hh = 0; hh < 2; ++hh)
#pragma unroll
    for (int ni = 0; ni < 16; ++ni) {
      int h = hh * 256 + ni * 16 + lrow;
      if (h < 500) {
#pragma unroll
        for (int j = 0; j < 4; ++j) {
          int t = tb + lhi * 4 + j;
          out[((size_t)(b * 256 + t)) * 500 + h] = o[hh][ni][j];
        }
      }
    }
}

extern "C" void kernel_launch(void* const* d_in, const int* in_sizes, int n_in,
                              void* d_out, int out_size, void* d_ws, size_t ws_size,
                              hipStream_t stream) {
  const float* x  = (const float*)d_in[0];
  const float* Wq = (const float*)d_in[1];
  const float* Wk = (const float*)d_in[2];
  const float* Wv = (const float*)d_in[3];
  float* out = (float*)d_out;

  u16* xb = (u16*)d_ws;                 // [65536][512] bf16
  u16* qb = xb + 33554432;              // [65536][512]
  u16* kb = qb + 33554432;              // [65536][512]
  u16* vT = kb + 33554432;              // [256][512][256]
  u16* Wt = vT + 33554432;              // [1536][512]
  float* cospair = (float*)(Wt + 786432); // [256][256]
  float* sinpair = cospair + 65536;       // [256][256]

  k_prep<<<16384 + 3072 + 256, 256, 0, stream>>>(x, Wq, Wk, Wv, xb, Wt,
                                                 cospair, sinpair);
  k_gemm_qkv<<<1536, 512, 0, stream>>>(xb, Wt, cospair, sinpair, qb, kb, vT);
  k_attn<<<512, 512, 0, stream>>>(qb, kb, vT, out);
}